// Round 6
// baseline (144.016 us; speedup 1.0000x reference)
//
#include <hip/hip_runtime.h>
#include <hip/hip_fp16.h>

#define N_NODES 50000
#define N_EDGES 800000
#define TOT_E   (N_EDGES + N_NODES)
#define NEG_SLOPE 0.2f
#define MB_SHIFT 8.0f   // fixed softmax shift: valid upper bound for e=as+ad (|e|<~3);
                        // softmax is shift-invariant so result is exact up to fp rounding.

#define SHIFT  6
#define NBUCK  ((N_NODES + 63) >> SHIFT)       // 782 buckets of 64 nodes
#define NBP    1024                             // padded scan width
#define CHUNK  4096                             // 208 binscatter blocks
#define EPT    (CHUNK / 256)                    // 16 edges per thread
#define NCHUNK ((TOT_E + CHUNK - 1) / CHUNK)
#define NGEMM1 ((N_NODES + 63) / 64)            // 782 GEMM1 blocks (BM=64)

// ---------- edge fetch (handles int32 or int64 edge_index; self-loops appended) ----------
__device__ __forceinline__ void get_edge(const void* edges, int flag64, long long i,
                                         int& src, int& dst) {
    if (i < N_EDGES) {
        if (flag64) {
            const long long* e = (const long long*)edges;
            src = (int)e[i];
            dst = (int)e[N_EDGES + i];
        } else {
            const int* e = (const int*)edges;
            src = e[i];
            dst = e[(long long)N_EDGES + i];
        }
    } else {
        src = dst = (int)(i - N_EDGES);
    }
}

__device__ __forceinline__ int get_dst(const void* edges, int flag64, long long i) {
    if (i < N_EDGES) {
        if (flag64) return (int)((const long long*)edges)[N_EDGES + i];
        return ((const int*)edges)[(long long)N_EDGES + i];
    }
    return (int)(i - N_EDGES);
}

// per-block edge-dtype detection: wave 0 checks first 64 int64 slots, one ballot.
__device__ __forceinline__ int detect64(const void* edges, int tid, int* sfl) {
    if (tid < 64) {
        long long v = ((const long long*)edges)[tid];
        unsigned long long ok = __ballot(v >= 0 && v < N_NODES);
        if (tid == 0) *sfl = (ok == ~0ull) ? 1 : 0;
    }
    __syncthreads();
    return *sfl;
}

// ---------- zero the global bucket histogram (3KB) ----------
__global__ __launch_bounds__(256) void k_zero(int* __restrict__ ghist) {
    int i = blockIdx.x * blockDim.x + threadIdx.x;
    if (i < NBUCK) ghist[i] = 0;
}

// ---------- bucket histogram: 416 blocks, LDS-aggregated, global atomic flush ----------
__global__ __launch_bounds__(256) void k_binhist(const void* edges, int* __restrict__ ghist) {
    __shared__ int h[NBUCK];
    __shared__ int sfl;
    const int tid = threadIdx.x;
    for (int i = tid; i < NBUCK; i += 256) h[i] = 0;
    const int fl = detect64(edges, tid, &sfl);   // includes __syncthreads()
    const int stride = gridDim.x * blockDim.x;
    for (long long i = (long long)blockIdx.x * blockDim.x + tid; i < TOT_E; i += stride)
        atomicAdd(&h[get_dst(edges, fl, i) >> SHIFT], 1);
    __syncthreads();
    for (int i = tid; i < NBUCK; i += 256)
        if (h[i]) atomicAdd(&ghist[i], h[i]);
}

// ---------- single-block scan of bucket histogram -> boffs, gcur ----------
__global__ __launch_bounds__(256) void k_bscan(const int* __restrict__ ghist,
                                               int* __restrict__ boffs,
                                               int* __restrict__ gcur) {
    __shared__ int sc[NBP];
    const int tid = threadIdx.x;
    for (int s = 0; s < 4; s++) {
        int i = tid + s * 256;
        sc[i] = (i < NBUCK) ? ghist[i] : 0;
    }
    __syncthreads();
    for (int off = 1; off < NBP; off <<= 1) {
        int t[4];
        for (int s = 0; s < 4; s++) {
            int a = tid + s * 256;
            t[s] = (a >= off) ? sc[a - off] : 0;
        }
        __syncthreads();
        for (int s = 0; s < 4; s++) sc[tid + s * 256] += t[s];
        __syncthreads();
    }
    for (int s = 0; s < 4; s++) {
        int i = tid + s * 256;
        if (i < NBUCK) {
            int e = sc[i] - ghist[i];   // exclusive
            boffs[i] = e;
            gcur[i]  = e;
        }
    }
    if (tid == 0) boffs[NBUCK] = sc[NBUCK - 1];
}

// ---------- chunked binscatter: group chunk's edges by bucket in LDS, write runs ----------
__global__ __launch_bounds__(256) void k_binscatter(const void* edges,
                                                    int* gcur, unsigned int* staging) {
    __shared__ int sc[NBP];        // counts -> inclusive scan
    __shared__ int so[NBP];        // original counts
    __shared__ int sr[NBUCK];      // running cursor (phase 3)
    __shared__ int gb[NBUCK];      // global base per bucket
    __shared__ unsigned int buf[CHUNK];
    __shared__ int sfl;
    const int tid = threadIdx.x;
    const int c0 = blockIdx.x * CHUNK;
    const int nE = min(CHUNK, TOT_E - c0);
    unsigned int pk[EPT];

    for (int s = 0; s < 4; s++) sc[tid + s * 256] = 0;
    for (int i = tid; i < NBUCK; i += 256) sr[i] = 0;
    const int fl = detect64(edges, tid, &sfl);   // includes __syncthreads()
    // phase 1: read edges, pack, count
#pragma unroll
    for (int j = 0; j < EPT; j++) {
        int li = j * 256 + tid;
        pk[j] = 0u;
        if (li < nE) {
            int src, dst;
            get_edge(edges, fl, (long long)(c0 + li), src, dst);
            pk[j] = ((unsigned int)dst << 16) | (unsigned int)src;
            atomicAdd(&sc[dst >> SHIFT], 1);
        }
    }
    __syncthreads();
    for (int s = 0; s < 4; s++) { int i = tid + s * 256; so[i] = sc[i]; }
    __syncthreads();
    // phase 2: inclusive scan of sc
    for (int off = 1; off < NBP; off <<= 1) {
        int t[4];
        for (int s = 0; s < 4; s++) {
            int a = tid + s * 256;
            t[s] = (a >= off) ? sc[a - off] : 0;
        }
        __syncthreads();
        for (int s = 0; s < 4; s++) sc[tid + s * 256] += t[s];
        __syncthreads();
    }
    // reserve global ranges
    for (int b = tid; b < NBUCK; b += 256)
        if (so[b]) gb[b] = atomicAdd(&gcur[b], so[b]);
    __syncthreads();
    // phase 3: place packed edges bucket-grouped in LDS
#pragma unroll
    for (int j = 0; j < EPT; j++) {
        int li = j * 256 + tid;
        if (li < nE) {
            int b = pk[j] >> (16 + SHIFT);
            int lofs = sc[b] - so[b];
            int pos = lofs + atomicAdd(&sr[b], 1);
            buf[pos] = pk[j];
        }
    }
    __syncthreads();
    // phase 4: write out; consecutive p within a bucket -> consecutive global
    for (int p = tid; p < nE; p += 256) {
        unsigned int e = buf[p];
        int b = e >> (16 + SHIFT);
        int lofs = sc[b] - so[b];
        staging[gb[b] + (p - lofs)] = e;
    }
}

// ---------- merged dispatch: GEMM1 blocks + bucketsort blocks (independent work) ----------
__global__ __launch_bounds__(256) void k_sortgemm(
        const unsigned int* __restrict__ staging, const int* __restrict__ boffs,
        int* __restrict__ offs, int* __restrict__ srt,
        const float* __restrict__ X, const float* __restrict__ W,
        const float* __restrict__ a_src, const float* __restrict__ a_dst,
        __half* __restrict__ H, float* __restrict__ as_, float* __restrict__ ad_) {
    const int tid = threadIdx.x;
    if (blockIdx.x >= NGEMM1) {
        // ----- bucketsort branch -----
        __shared__ int cnt[64];
        __shared__ int base[64];
        __shared__ int cur[64];
        const int b = blockIdx.x - NGEMM1;
        const int node0 = b << SHIFT;
        const int nn = min(64, N_NODES - node0);
        if (tid < 64) cnt[tid] = 0;
        __syncthreads();
        const int beg = boffs[b], end = boffs[b + 1];
        for (int i = beg + tid; i < end; i += 256)
            atomicAdd(&cnt[(staging[i] >> 16) - node0], 1);
        __syncthreads();
        if (tid < 64) {
            int v = cnt[tid];
            int incl = v;
#pragma unroll
            for (int off = 1; off < 64; off <<= 1) {
                int t = __shfl_up(incl, off, 64);
                if (tid >= off) incl += t;
            }
            base[tid] = beg + incl - v;
            cur[tid] = 0;
            if (tid < nn) offs[node0 + tid] = beg + incl - v;
        }
        __syncthreads();
        for (int i = beg + tid; i < end; i += 256) {
            unsigned int e = staging[i];
            int dl = (int)(e >> 16) - node0;
            int pos = base[dl] + atomicAdd(&cur[dl], 1);
            srt[pos] = (int)(e & 0xFFFFu);
        }
        if (b == 0 && tid == 0) offs[N_NODES] = boffs[NBUCK];
        return;
    }
    // ----- GEMM1 branch: K=128, N=64, BM=64, BK=32 -----
    constexpr int K = 128, N = 64, BM = 64, BK = 32;
    constexpr int TCOLS = N / 4;                 // 16
    constexpr int KPT = (BM * BK) / 256;         // 8
    __shared__ float Xs[BK][BM];
    __shared__ float Ws[BK][N];
    const int bid  = blockIdx.x;
    const int tcol = tid % TCOLS;
    const int trow = tid / TCOLS;
    const int node0 = bid * BM;
    const int r0 = trow * 4;
    const int c0 = tcol * 4;
    float acc[4][4] = {};

    const int sm = tid % BM;
    const int skb = (tid / BM) * KPT;
    const int srow = (node0 + sm < N_NODES) ? (node0 + sm) : (N_NODES - 1);

    for (int k0 = 0; k0 < K; k0 += BK) {
        const float* xp = X + (long long)srow * K + k0 + skb;
#pragma unroll
        for (int j = 0; j < KPT; j += 4) {
            float4 v = *(const float4*)(xp + j);
            Xs[skb + j + 0][sm] = v.x;
            Xs[skb + j + 1][sm] = v.y;
            Xs[skb + j + 2][sm] = v.z;
            Xs[skb + j + 3][sm] = v.w;
        }
#pragma unroll
        for (int i = tid; i < BK * N / 4; i += 256)
            ((float4*)Ws)[i] = ((const float4*)W)[(k0 * N) / 4 + i];
        __syncthreads();
#pragma unroll 8
        for (int k = 0; k < BK; ++k) {
            float4 xa = *(const float4*)&Xs[k][r0];
            float4 wb = *(const float4*)&Ws[k][c0];
            float xr[4] = {xa.x, xa.y, xa.z, xa.w};
            float wc[4] = {wb.x, wb.y, wb.z, wb.w};
#pragma unroll
            for (int i = 0; i < 4; ++i)
#pragma unroll
                for (int j = 0; j < 4; ++j)
                    acc[i][j] += xr[i] * wc[j];
        }
        __syncthreads();
    }

    const float4 asv = *(const float4*)(a_src + c0);
    const float4 adv = *(const float4*)(a_dst + c0);
    const int rbase = node0 + r0;
    float vsr[4], vdr[4];
#pragma unroll
    for (int i = 0; i < 4; ++i) {
        float vs = acc[i][0] * asv.x + acc[i][1] * asv.y + acc[i][2] * asv.z + acc[i][3] * asv.w;
        float vd = acc[i][0] * adv.x + acc[i][1] * adv.y + acc[i][2] * adv.z + acc[i][3] * adv.w;
#pragma unroll
        for (int off = 1; off < TCOLS; off <<= 1) {
            vs += __shfl_xor(vs, off, 64);
            vd += __shfl_xor(vd, off, 64);
        }
        vsr[i] = vs; vdr[i] = vd;
        if (rbase + i < N_NODES) {
            __half2 q0 = __floats2half2_rn(acc[i][0], acc[i][1]);
            __half2 q1 = __floats2half2_rn(acc[i][2], acc[i][3]);
            uint2 raw;
            raw.x = *(unsigned int*)&q0;
            raw.y = *(unsigned int*)&q1;
            *(uint2*)(H + (long long)(rbase + i) * N + c0) = raw;
        }
    }
    if (tcol == 0) {
#pragma unroll
        for (int i = 0; i < 4; ++i) {
            if (rbase + i < N_NODES) {
                as_[rbase + i] = vsr[i];
                ad_[rbase + i] = vdr[i];
            }
        }
    }
}

// ---------- register-tiled GEMM (H = X @ W, stored fp16) + attention dots (layer 2) ----------
template<int K, int N, int BM, int BK>
__global__ __launch_bounds__(256) void k_gemm_att(
        const float* __restrict__ X, const float* __restrict__ W,
        const float* __restrict__ a_src, const float* __restrict__ a_dst,
        __half* __restrict__ H, float* __restrict__ as_, float* __restrict__ ad_) {
    constexpr int TCOLS = N / 4;
    __shared__ float Xs[BK][BM];
    __shared__ float Ws[BK][N];
    const int tid  = threadIdx.x;
    const int tcol = tid % TCOLS;
    const int trow = tid / TCOLS;
    const int node0 = blockIdx.x * BM;
    const int r0 = trow * 4;
    const int c0 = tcol * 4;
    float acc[4][4] = {};

    constexpr int KPT = (BM * BK) / 256;
    const int sm = tid % BM;
    const int skb = (tid / BM) * KPT;
    const int srow = (node0 + sm < N_NODES) ? (node0 + sm) : (N_NODES - 1);

    for (int k0 = 0; k0 < K; k0 += BK) {
        const float* xp = X + (long long)srow * K + k0 + skb;
#pragma unroll
        for (int j = 0; j < KPT; j += 4) {
            float4 v = *(const float4*)(xp + j);
            Xs[skb + j + 0][sm] = v.x;
            Xs[skb + j + 1][sm] = v.y;
            Xs[skb + j + 2][sm] = v.z;
            Xs[skb + j + 3][sm] = v.w;
        }
#pragma unroll
        for (int i = tid; i < BK * N / 4; i += 256)
            ((float4*)Ws)[i] = ((const float4*)W)[(k0 * N) / 4 + i];
        __syncthreads();
#pragma unroll 8
        for (int k = 0; k < BK; ++k) {
            float4 xa = *(const float4*)&Xs[k][r0];
            float4 wb = *(const float4*)&Ws[k][c0];
            float xr[4] = {xa.x, xa.y, xa.z, xa.w};
            float wc[4] = {wb.x, wb.y, wb.z, wb.w};
#pragma unroll
            for (int i = 0; i < 4; ++i)
#pragma unroll
                for (int j = 0; j < 4; ++j)
                    acc[i][j] += xr[i] * wc[j];
        }
        __syncthreads();
    }

    const float4 asv = *(const float4*)(a_src + c0);
    const float4 adv = *(const float4*)(a_dst + c0);
    const int rbase = node0 + r0;
    float vsr[4], vdr[4];
#pragma unroll
    for (int i = 0; i < 4; ++i) {
        float vs = acc[i][0] * asv.x + acc[i][1] * asv.y + acc[i][2] * asv.z + acc[i][3] * asv.w;
        float vd = acc[i][0] * adv.x + acc[i][1] * adv.y + acc[i][2] * adv.z + acc[i][3] * adv.w;
#pragma unroll
        for (int off = 1; off < TCOLS; off <<= 1) {
            vs += __shfl_xor(vs, off, 64);
            vd += __shfl_xor(vd, off, 64);
        }
        vsr[i] = vs; vdr[i] = vd;
        if (rbase + i < N_NODES) {
            __half2 q0 = __floats2half2_rn(acc[i][0], acc[i][1]);
            __half2 q1 = __floats2half2_rn(acc[i][2], acc[i][3]);
            uint2 raw;
            raw.x = *(unsigned int*)&q0;
            raw.y = *(unsigned int*)&q1;
            *(uint2*)(H + (long long)(rbase + i) * N + c0) = raw;
        }
    }
    if (tcol == 0) {
#pragma unroll
        for (int i = 0; i < 4; ++i) {
            if (rbase + i < N_NODES) {
                as_[rbase + i] = vsr[i];
                ad_[rbase + i] = vdr[i];
            }
        }
    }
}

// ---------- fused per-node single pass: deep-pipelined fp16 H gather ----------
// ONE WAVE PER NODE.
// Phase A: one edge per lane -> coalesced srt load, one as_ gather per 64 edges,
//          wave-parallel leakyrelu+exp; (src byte-offset, p) stay in registers.
// Phase B: ALL of the batch's row loads are issued up-front (up to NSLOT=8 uint4
//          loads in flight per lane; statically-indexed register array, wave-uniform
//          guards), THEN consumed. Raises memory-level parallelism 4x per wave --
//          the h1/g2 gathers miss the 4MB per-XCD L2 (FETCH 35.5MB measured) and
//          pay ~900cy HBM latency; 2-deep pipelining left that latency exposed.
template<int C, bool ELU>
__global__ __launch_bounds__(256) void k_node(
        const int* __restrict__ offs, const int* __restrict__ srt,
        const float* __restrict__ as_, const float* __restrict__ ad_,
        const __half* __restrict__ H, const float* __restrict__ bias,
        float* __restrict__ out) {
    constexpr int G     = C / 8;      // lanes per row (8 for C=64, 4 for C=32)
    constexpr int NG    = 64 / G;     // rows per slot (8 or 16)
    constexpr int NSLOT = 64 / NG;    // slots per 64-edge batch (8 or 4)
    const int node = (int)(((long long)blockIdx.x * blockDim.x + threadIdx.x) >> 6);
    if (node >= N_NODES) return;
    const int lane = threadIdx.x & 63;
    const int g  = lane / G;
    const int cl = lane % G;
    const int beg = offs[node], end = offs[node + 1];
    const int deg = end - beg;
    const float adn = ad_[node];
    const char* Hb = (const char*)H + cl * 16;   // per-lane channel base (bytes)
    float acc[8] = {};
    float ssum = 0.f;

    for (int base = 0; base < deg; base += 64) {
        const int nb = min(64, deg - base);
        // ---- phase A: one edge per lane ----
        int sB = 0;          // src row as BYTE offset (pre-scaled before broadcast)
        float p = 0.f;
        if (lane < nb) {
            int s = srt[beg + base + lane];
            float e = as_[s] + adn;
            e = (e > 0.f) ? e : NEG_SLOPE * e;
            p = __expf(e - MB_SHIFT);
            sB = s * (int)(C * sizeof(__half));
        }
        ssum += p;
        // ---- phase B step 1: issue ALL loads (wave-uniform slot guards; static regs) ----
        uint4 r[NSLOT];
        float pp[NSLOT];
#pragma unroll
        for (int t = 0; t < NSLOT; t++) {
            if (t * NG < nb) {
                const int o = __shfl(sB, t * NG + g, 64);
                pp[t] = __shfl(p, t * NG + g, 64);
                r[t] = *(const uint4*)(Hb + o);   // lanes past nb: o=0,pp=0 (benign row-0)
            }
        }
        // ---- phase B step 2: consume ----
#pragma unroll
        for (int t = 0; t < NSLOT; t++) {
            if (t * NG < nb) {
                const float pt = pp[t];
                float2 f;
                f = __half22float2(*(const __half2*)&r[t].x); acc[0] += pt * f.x; acc[1] += pt * f.y;
                f = __half22float2(*(const __half2*)&r[t].y); acc[2] += pt * f.x; acc[3] += pt * f.y;
                f = __half22float2(*(const __half2*)&r[t].z); acc[4] += pt * f.x; acc[5] += pt * f.y;
                f = __half22float2(*(const __half2*)&r[t].w); acc[6] += pt * f.x; acc[7] += pt * f.y;
            }
        }
    }
    // ssum: full 64-lane reduce (phase A spread p across all lanes)
#pragma unroll
    for (int off = 1; off < 64; off <<= 1)
        ssum += __shfl_xor(ssum, off, 64);
    // acc: reduce across the NG row-groups
#pragma unroll
    for (int off = G; off < 64; off <<= 1)
#pragma unroll
        for (int q = 0; q < 8; q++)
            acc[q] += __shfl_xor(acc[q], off, 64);
    if (lane < G) {
        const float inv = 1.f / (ssum + 1e-30f);
        float v[8];
#pragma unroll
        for (int q = 0; q < 8; q++) {
            v[q] = acc[q] * inv + bias[cl * 8 + q];
            if (ELU) v[q] = (v[q] > 0.f) ? v[q] : expm1f(v[q]);
        }
        float4 lo = {v[0], v[1], v[2], v[3]};
        float4 hi = {v[4], v[5], v[6], v[7]};
        *(float4*)(out + (long long)node * C + cl * 8)     = lo;
        *(float4*)(out + (long long)node * C + cl * 8 + 4) = hi;
    }
}

extern "C" void kernel_launch(void* const* d_in, const int* in_sizes, int n_in,
                              void* d_out, int out_size, void* d_ws, size_t ws_size,
                              hipStream_t stream) {
    const float* x      = (const float*)d_in[0];
    const void*  edges  = d_in[1];
    const float* W1     = (const float*)d_in[2];
    const float* a_src1 = (const float*)d_in[3];
    const float* a_dst1 = (const float*)d_in[4];
    const float* b1     = (const float*)d_in[5];
    const float* W2     = (const float*)d_in[6];
    const float* a_src2 = (const float*)d_in[7];
    const float* a_dst2 = (const float*)d_in[8];
    const float* b2     = (const float*)d_in[9];

    char* ws = (char*)d_ws;
    size_t off = 0;
    auto alloc = [&](size_t bytes) { char* p = ws + off; off += (bytes + 255) & ~size_t(255); return p; };
    __half*       h1      = (__half*)      alloc((size_t)N_NODES * 64 * 2);  // fp16 H, layer 1
    float*        h2      = (float*)       alloc((size_t)N_NODES * 64 * 4);  // layer-1 out (fp32)
    float*        as1     = (float*)       alloc((size_t)N_NODES * 4);
    float*        ad1     = (float*)       alloc((size_t)N_NODES * 4);
    float*        as2     = (float*)       alloc((size_t)N_NODES * 4);
    float*        ad2     = (float*)       alloc((size_t)N_NODES * 4);
    int*          ghist   = (int*)         alloc((size_t)NBUCK * 4);
    int*          boffs   = (int*)         alloc((size_t)(NBUCK + 1) * 4);
    int*          gcur    = (int*)         alloc((size_t)NBUCK * 4);
    int*          offs    = (int*)         alloc((size_t)(N_NODES + 1) * 4);
    unsigned int* staging = (unsigned int*)alloc((size_t)TOT_E * 4);
    int*          srt     = (int*)         alloc((size_t)(TOT_E + 8) * 4);
    float*        out     = (float*)d_out;
    __half*       g2      = h1;  // h1 dead after k_node<64>; reuse (3.2MB needed < 6.4MB)

    const int NODE_BLOCKS = (N_NODES * 64 + 255) / 256;  // one wave per node

    // binned CSR build front (zero + 416-block atomic histogram: measured-fast form)
    k_zero<<<(NBUCK + 255) / 256, 256, 0, stream>>>(ghist);
    k_binhist<<<416, 256, 0, stream>>>(edges, ghist);
    k_bscan<<<1, 256, 0, stream>>>(ghist, boffs, gcur);
    k_binscatter<<<NCHUNK, 256, 0, stream>>>(edges, gcur, staging);

    // merged: layer-1 GEMM (independent) + bucketsort (needs binscatter) in ONE dispatch;
    // both outputs feed k_node<64>.
    k_sortgemm<<<NGEMM1 + NBUCK, 256, 0, stream>>>(
        staging, boffs, offs, srt, x, W1, a_src1, a_dst1, h1, as1, ad1);
    k_node<64, true><<<NODE_BLOCKS, 256, 0, stream>>>(offs, srt, as1, ad1, h1, b1, h2);

    // layer 2: K=64, N=32, BM=128, BK=32
    k_gemm_att<64, 32, 128, 32><<<(N_NODES + 127) / 128, 256, 0, stream>>>(
        h2, W2, a_src2, a_dst2, g2, as2, ad2);
    k_node<32, false><<<NODE_BLOCKS, 256, 0, stream>>>(offs, srt, as2, ad2, g2, b2, out);
}

// Round 7
// 117.539 us; speedup vs baseline: 1.2253x; 1.2253x over previous
//
#include <hip/hip_runtime.h>
#include <hip/hip_fp16.h>

#define N_NODES 50000
#define N_EDGES 800000
#define TOT_E   (N_EDGES + N_NODES)
#define NEG_SLOPE 0.2f
#define MB_SHIFT 8.0f   // fixed softmax shift: valid upper bound for e=as+ad (|e|<~3);
                        // softmax is shift-invariant so result is exact up to fp rounding.

#define SHIFT  6
#define NBUCK  ((N_NODES + 63) >> SHIFT)       // 782 buckets of 64 nodes
#define NBP    1024                             // padded scan width
#define CHUNK  4096                             // 208 binscatter blocks
#define EPT    (CHUNK / 256)                    // 16 edges per thread
#define NCHUNK ((TOT_E + CHUNK - 1) / CHUNK)
#define NGEMM1 ((N_NODES + 63) / 64)            // 782 GEMM1 blocks (BM=64)

// ---------- edge fetch (handles int32 or int64 edge_index; self-loops appended) ----------
__device__ __forceinline__ void get_edge(const void* edges, int flag64, long long i,
                                         int& src, int& dst) {
    if (i < N_EDGES) {
        if (flag64) {
            const long long* e = (const long long*)edges;
            src = (int)e[i];
            dst = (int)e[N_EDGES + i];
        } else {
            const int* e = (const int*)edges;
            src = e[i];
            dst = e[(long long)N_EDGES + i];
        }
    } else {
        src = dst = (int)(i - N_EDGES);
    }
}

__device__ __forceinline__ int get_dst(const void* edges, int flag64, long long i) {
    if (i < N_EDGES) {
        if (flag64) return (int)((const long long*)edges)[N_EDGES + i];
        return ((const int*)edges)[(long long)N_EDGES + i];
    }
    return (int)(i - N_EDGES);
}

// per-block edge-dtype detection: wave 0 checks first 64 int64 slots, one ballot.
__device__ __forceinline__ int detect64(const void* edges, int tid, int* sfl) {
    if (tid < 64) {
        long long v = ((const long long*)edges)[tid];
        unsigned long long ok = __ballot(v >= 0 && v < N_NODES);
        if (tid == 0) *sfl = (ok == ~0ull) ? 1 : 0;
    }
    __syncthreads();
    return *sfl;
}

// ---------- zero the global bucket histogram (3KB) ----------
__global__ __launch_bounds__(256) void k_zero(int* __restrict__ ghist) {
    int i = blockIdx.x * blockDim.x + threadIdx.x;
    if (i < NBUCK) ghist[i] = 0;
}

// ---------- bucket histogram: 416 blocks, LDS-aggregated, global atomic flush ----------
__global__ __launch_bounds__(256) void k_binhist(const void* edges, int* __restrict__ ghist) {
    __shared__ int h[NBUCK];
    __shared__ int sfl;
    const int tid = threadIdx.x;
    for (int i = tid; i < NBUCK; i += 256) h[i] = 0;
    const int fl = detect64(edges, tid, &sfl);   // includes __syncthreads()
    const int stride = gridDim.x * blockDim.x;
    for (long long i = (long long)blockIdx.x * blockDim.x + tid; i < TOT_E; i += stride)
        atomicAdd(&h[get_dst(edges, fl, i) >> SHIFT], 1);
    __syncthreads();
    for (int i = tid; i < NBUCK; i += 256)
        if (h[i]) atomicAdd(&ghist[i], h[i]);
}

// ---------- single-block scan of bucket histogram -> boffs, gcur ----------
__global__ __launch_bounds__(256) void k_bscan(const int* __restrict__ ghist,
                                               int* __restrict__ boffs,
                                               int* __restrict__ gcur) {
    __shared__ int sc[NBP];
    const int tid = threadIdx.x;
    for (int s = 0; s < 4; s++) {
        int i = tid + s * 256;
        sc[i] = (i < NBUCK) ? ghist[i] : 0;
    }
    __syncthreads();
    for (int off = 1; off < NBP; off <<= 1) {
        int t[4];
        for (int s = 0; s < 4; s++) {
            int a = tid + s * 256;
            t[s] = (a >= off) ? sc[a - off] : 0;
        }
        __syncthreads();
        for (int s = 0; s < 4; s++) sc[tid + s * 256] += t[s];
        __syncthreads();
    }
    for (int s = 0; s < 4; s++) {
        int i = tid + s * 256;
        if (i < NBUCK) {
            int e = sc[i] - ghist[i];   // exclusive
            boffs[i] = e;
            gcur[i]  = e;
        }
    }
    if (tid == 0) boffs[NBUCK] = sc[NBUCK - 1];
}

// ---------- chunked binscatter: group chunk's edges by bucket in LDS, write runs ----------
__global__ __launch_bounds__(256) void k_binscatter(const void* edges,
                                                    int* gcur, unsigned int* staging) {
    __shared__ int sc[NBP];        // counts -> inclusive scan
    __shared__ int so[NBP];        // original counts
    __shared__ int sr[NBUCK];      // running cursor (phase 3)
    __shared__ int gb[NBUCK];      // global base per bucket
    __shared__ unsigned int buf[CHUNK];
    __shared__ int sfl;
    const int tid = threadIdx.x;
    const int c0 = blockIdx.x * CHUNK;
    const int nE = min(CHUNK, TOT_E - c0);
    unsigned int pk[EPT];

    for (int s = 0; s < 4; s++) sc[tid + s * 256] = 0;
    for (int i = tid; i < NBUCK; i += 256) sr[i] = 0;
    const int fl = detect64(edges, tid, &sfl);   // includes __syncthreads()
    // phase 1: read edges, pack, count
#pragma unroll
    for (int j = 0; j < EPT; j++) {
        int li = j * 256 + tid;
        pk[j] = 0u;
        if (li < nE) {
            int src, dst;
            get_edge(edges, fl, (long long)(c0 + li), src, dst);
            pk[j] = ((unsigned int)dst << 16) | (unsigned int)src;
            atomicAdd(&sc[dst >> SHIFT], 1);
        }
    }
    __syncthreads();
    for (int s = 0; s < 4; s++) { int i = tid + s * 256; so[i] = sc[i]; }
    __syncthreads();
    // phase 2: inclusive scan of sc
    for (int off = 1; off < NBP; off <<= 1) {
        int t[4];
        for (int s = 0; s < 4; s++) {
            int a = tid + s * 256;
            t[s] = (a >= off) ? sc[a - off] : 0;
        }
        __syncthreads();
        for (int s = 0; s < 4; s++) sc[tid + s * 256] += t[s];
        __syncthreads();
    }
    // reserve global ranges
    for (int b = tid; b < NBUCK; b += 256)
        if (so[b]) gb[b] = atomicAdd(&gcur[b], so[b]);
    __syncthreads();
    // phase 3: place packed edges bucket-grouped in LDS
#pragma unroll
    for (int j = 0; j < EPT; j++) {
        int li = j * 256 + tid;
        if (li < nE) {
            int b = pk[j] >> (16 + SHIFT);
            int lofs = sc[b] - so[b];
            int pos = lofs + atomicAdd(&sr[b], 1);
            buf[pos] = pk[j];
        }
    }
    __syncthreads();
    // phase 4: write out; consecutive p within a bucket -> consecutive global
    for (int p = tid; p < nE; p += 256) {
        unsigned int e = buf[p];
        int b = e >> (16 + SHIFT);
        int lofs = sc[b] - so[b];
        staging[gb[b] + (p - lofs)] = e;
    }
}

// ---------- merged dispatch: GEMM1 blocks + bucketsort blocks (independent work) ----------
__global__ __launch_bounds__(256) void k_sortgemm(
        const unsigned int* __restrict__ staging, const int* __restrict__ boffs,
        int* __restrict__ offs, int* __restrict__ srt,
        const float* __restrict__ X, const float* __restrict__ W,
        const float* __restrict__ a_src, const float* __restrict__ a_dst,
        __half* __restrict__ H, float* __restrict__ as_, float* __restrict__ ad_) {
    const int tid = threadIdx.x;
    if (blockIdx.x >= NGEMM1) {
        // ----- bucketsort branch -----
        __shared__ int cnt[64];
        __shared__ int base[64];
        __shared__ int cur[64];
        const int b = blockIdx.x - NGEMM1;
        const int node0 = b << SHIFT;
        const int nn = min(64, N_NODES - node0);
        if (tid < 64) cnt[tid] = 0;
        __syncthreads();
        const int beg = boffs[b], end = boffs[b + 1];
        for (int i = beg + tid; i < end; i += 256)
            atomicAdd(&cnt[(staging[i] >> 16) - node0], 1);
        __syncthreads();
        if (tid < 64) {
            int v = cnt[tid];
            int incl = v;
#pragma unroll
            for (int off = 1; off < 64; off <<= 1) {
                int t = __shfl_up(incl, off, 64);
                if (tid >= off) incl += t;
            }
            base[tid] = beg + incl - v;
            cur[tid] = 0;
            if (tid < nn) offs[node0 + tid] = beg + incl - v;
        }
        __syncthreads();
        for (int i = beg + tid; i < end; i += 256) {
            unsigned int e = staging[i];
            int dl = (int)(e >> 16) - node0;
            int pos = base[dl] + atomicAdd(&cur[dl], 1);
            srt[pos] = (int)(e & 0xFFFFu);
        }
        if (b == 0 && tid == 0) offs[N_NODES] = boffs[NBUCK];
        return;
    }
    // ----- GEMM1 branch: K=128, N=64, BM=64, BK=32 -----
    constexpr int K = 128, N = 64, BM = 64, BK = 32;
    constexpr int TCOLS = N / 4;                 // 16
    constexpr int KPT = (BM * BK) / 256;         // 8
    __shared__ float Xs[BK][BM];
    __shared__ float Ws[BK][N];
    const int bid  = blockIdx.x;
    const int tcol = tid % TCOLS;
    const int trow = tid / TCOLS;
    const int node0 = bid * BM;
    const int r0 = trow * 4;
    const int c0 = tcol * 4;
    float acc[4][4] = {};

    const int sm = tid % BM;
    const int skb = (tid / BM) * KPT;
    const int srow = (node0 + sm < N_NODES) ? (node0 + sm) : (N_NODES - 1);

    for (int k0 = 0; k0 < K; k0 += BK) {
        const float* xp = X + (long long)srow * K + k0 + skb;
#pragma unroll
        for (int j = 0; j < KPT; j += 4) {
            float4 v = *(const float4*)(xp + j);
            Xs[skb + j + 0][sm] = v.x;
            Xs[skb + j + 1][sm] = v.y;
            Xs[skb + j + 2][sm] = v.z;
            Xs[skb + j + 3][sm] = v.w;
        }
#pragma unroll
        for (int i = tid; i < BK * N / 4; i += 256)
            ((float4*)Ws)[i] = ((const float4*)W)[(k0 * N) / 4 + i];
        __syncthreads();
#pragma unroll 8
        for (int k = 0; k < BK; ++k) {
            float4 xa = *(const float4*)&Xs[k][r0];
            float4 wb = *(const float4*)&Ws[k][c0];
            float xr[4] = {xa.x, xa.y, xa.z, xa.w};
            float wc[4] = {wb.x, wb.y, wb.z, wb.w};
#pragma unroll
            for (int i = 0; i < 4; ++i)
#pragma unroll
                for (int j = 0; j < 4; ++j)
                    acc[i][j] += xr[i] * wc[j];
        }
        __syncthreads();
    }

    const float4 asv = *(const float4*)(a_src + c0);
    const float4 adv = *(const float4*)(a_dst + c0);
    const int rbase = node0 + r0;
    float vsr[4], vdr[4];
#pragma unroll
    for (int i = 0; i < 4; ++i) {
        float vs = acc[i][0] * asv.x + acc[i][1] * asv.y + acc[i][2] * asv.z + acc[i][3] * asv.w;
        float vd = acc[i][0] * adv.x + acc[i][1] * adv.y + acc[i][2] * adv.z + acc[i][3] * adv.w;
#pragma unroll
        for (int off = 1; off < TCOLS; off <<= 1) {
            vs += __shfl_xor(vs, off, 64);
            vd += __shfl_xor(vd, off, 64);
        }
        vsr[i] = vs; vdr[i] = vd;
        if (rbase + i < N_NODES) {
            __half2 q0 = __floats2half2_rn(acc[i][0], acc[i][1]);
            __half2 q1 = __floats2half2_rn(acc[i][2], acc[i][3]);
            uint2 raw;
            raw.x = *(unsigned int*)&q0;
            raw.y = *(unsigned int*)&q1;
            *(uint2*)(H + (long long)(rbase + i) * N + c0) = raw;
        }
    }
    if (tcol == 0) {
#pragma unroll
        for (int i = 0; i < 4; ++i) {
            if (rbase + i < N_NODES) {
                as_[rbase + i] = vsr[i];
                ad_[rbase + i] = vdr[i];
            }
        }
    }
}

// ---------- register-tiled GEMM (H = X @ W, stored fp16) + attention dots (layer 2) ----------
template<int K, int N, int BM, int BK>
__global__ __launch_bounds__(256) void k_gemm_att(
        const float* __restrict__ X, const float* __restrict__ W,
        const float* __restrict__ a_src, const float* __restrict__ a_dst,
        __half* __restrict__ H, float* __restrict__ as_, float* __restrict__ ad_) {
    constexpr int TCOLS = N / 4;
    __shared__ float Xs[BK][BM];
    __shared__ float Ws[BK][N];
    const int tid  = threadIdx.x;
    const int tcol = tid % TCOLS;
    const int trow = tid / TCOLS;
    const int node0 = blockIdx.x * BM;
    const int r0 = trow * 4;
    const int c0 = tcol * 4;
    float acc[4][4] = {};

    constexpr int KPT = (BM * BK) / 256;
    const int sm = tid % BM;
    const int skb = (tid / BM) * KPT;
    const int srow = (node0 + sm < N_NODES) ? (node0 + sm) : (N_NODES - 1);

    for (int k0 = 0; k0 < K; k0 += BK) {
        const float* xp = X + (long long)srow * K + k0 + skb;
#pragma unroll
        for (int j = 0; j < KPT; j += 4) {
            float4 v = *(const float4*)(xp + j);
            Xs[skb + j + 0][sm] = v.x;
            Xs[skb + j + 1][sm] = v.y;
            Xs[skb + j + 2][sm] = v.z;
            Xs[skb + j + 3][sm] = v.w;
        }
#pragma unroll
        for (int i = tid; i < BK * N / 4; i += 256)
            ((float4*)Ws)[i] = ((const float4*)W)[(k0 * N) / 4 + i];
        __syncthreads();
#pragma unroll 8
        for (int k = 0; k < BK; ++k) {
            float4 xa = *(const float4*)&Xs[k][r0];
            float4 wb = *(const float4*)&Ws[k][c0];
            float xr[4] = {xa.x, xa.y, xa.z, xa.w};
            float wc[4] = {wb.x, wb.y, wb.z, wb.w};
#pragma unroll
            for (int i = 0; i < 4; ++i)
#pragma unroll
                for (int j = 0; j < 4; ++j)
                    acc[i][j] += xr[i] * wc[j];
        }
        __syncthreads();
    }

    const float4 asv = *(const float4*)(a_src + c0);
    const float4 adv = *(const float4*)(a_dst + c0);
    const int rbase = node0 + r0;
    float vsr[4], vdr[4];
#pragma unroll
    for (int i = 0; i < 4; ++i) {
        float vs = acc[i][0] * asv.x + acc[i][1] * asv.y + acc[i][2] * asv.z + acc[i][3] * asv.w;
        float vd = acc[i][0] * adv.x + acc[i][1] * adv.y + acc[i][2] * adv.z + acc[i][3] * adv.w;
#pragma unroll
        for (int off = 1; off < TCOLS; off <<= 1) {
            vs += __shfl_xor(vs, off, 64);
            vd += __shfl_xor(vd, off, 64);
        }
        vsr[i] = vs; vdr[i] = vd;
        if (rbase + i < N_NODES) {
            __half2 q0 = __floats2half2_rn(acc[i][0], acc[i][1]);
            __half2 q1 = __floats2half2_rn(acc[i][2], acc[i][3]);
            uint2 raw;
            raw.x = *(unsigned int*)&q0;
            raw.y = *(unsigned int*)&q1;
            *(uint2*)(H + (long long)(rbase + i) * N + c0) = raw;
        }
    }
    if (tcol == 0) {
#pragma unroll
        for (int i = 0; i < 4; ++i) {
            if (rbase + i < N_NODES) {
                as_[rbase + i] = vsr[i];
                ad_[rbase + i] = vdr[i];
            }
        }
    }
}

// ---------- fused per-node single pass: two-phase + fold-reduce epilogue ----------
// ONE WAVE PER NODE.
// Phase A/B: round-5 form (measured 40.3us): batched edge scalars, 2x-unrolled
//            uint4 gather loop.
// Epilogue:  FOLD-reduce across row-groups (send the discarded half, keep the owned
//            half) -> 7 DS ops for C=64 / 8 for C=32 instead of 24/32 butterfly shfls.
//            Each lane ends owning exactly ONE output channel
//            (ch = cl*8 + b0*4 + b1*2 + b2 from its group bits -> bijection), so the
//            epilogue is full-width: per-lane bias/ELU + one coalesced 4B store.
template<int C, bool ELU>
__global__ __launch_bounds__(256) void k_node(
        const int* __restrict__ offs, const int* __restrict__ srt,
        const float* __restrict__ as_, const float* __restrict__ ad_,
        const __half* __restrict__ H, const float* __restrict__ bias,
        float* __restrict__ out) {
    constexpr int G  = C / 8;    // lanes per row (8 for C=64, 4 for C=32)
    constexpr int NG = 64 / G;   // rows gathered per iteration (8 or 16)
    const int node = (int)(((long long)blockIdx.x * blockDim.x + threadIdx.x) >> 6);
    if (node >= N_NODES) return;
    const int lane = threadIdx.x & 63;
    const int g  = lane / G;
    const int cl = lane % G;
    const int beg = offs[node], end = offs[node + 1];
    const int deg = end - beg;
    const float adn = ad_[node];
    float acc[8] = {};
    float ssum = 0.f;

    for (int base = 0; base < deg; base += 64) {
        const int nb = min(64, deg - base);
        // ---- phase A: one edge per lane ----
        int s = 0;
        float p = 0.f;
        if (lane < nb) {
            s = srt[beg + base + lane];
            float e = as_[s] + adn;
            e = (e > 0.f) ? e : NEG_SLOPE * e;
            p = __expf(e - MB_SHIFT);
        }
        ssum += p;
        // ---- phase B: gather-only loop; lanes with index >= nb carry p=0 (benign row-0 read) ----
        int j = 0;
        for (; j + NG < nb; j += 2 * NG) {
            const int i0 = j + g, i1 = j + NG + g;
            const int   s0 = __shfl(s, i0, 64);
            const int   s1 = __shfl(s, i1, 64);
            const float p0 = __shfl(p, i0, 64);
            const float p1 = __shfl(p, i1, 64);
            const uint4 ra = *(const uint4*)(H + (long long)s0 * C + cl * 8);
            const uint4 rb = *(const uint4*)(H + (long long)s1 * C + cl * 8);
            float2 f;
            f = __half22float2(*(const __half2*)&ra.x); acc[0] += p0 * f.x; acc[1] += p0 * f.y;
            f = __half22float2(*(const __half2*)&ra.y); acc[2] += p0 * f.x; acc[3] += p0 * f.y;
            f = __half22float2(*(const __half2*)&ra.z); acc[4] += p0 * f.x; acc[5] += p0 * f.y;
            f = __half22float2(*(const __half2*)&ra.w); acc[6] += p0 * f.x; acc[7] += p0 * f.y;
            f = __half22float2(*(const __half2*)&rb.x); acc[0] += p1 * f.x; acc[1] += p1 * f.y;
            f = __half22float2(*(const __half2*)&rb.y); acc[2] += p1 * f.x; acc[3] += p1 * f.y;
            f = __half22float2(*(const __half2*)&rb.z); acc[4] += p1 * f.x; acc[5] += p1 * f.y;
            f = __half22float2(*(const __half2*)&rb.w); acc[6] += p1 * f.x; acc[7] += p1 * f.y;
        }
        if (j < nb) {
            const int i0 = j + g;
            const int   s0 = __shfl(s, i0, 64);
            const float p0 = __shfl(p, i0, 64);
            const uint4 ra = *(const uint4*)(H + (long long)s0 * C + cl * 8);
            float2 f;
            f = __half22float2(*(const __half2*)&ra.x); acc[0] += p0 * f.x; acc[1] += p0 * f.y;
            f = __half22float2(*(const __half2*)&ra.y); acc[2] += p0 * f.x; acc[3] += p0 * f.y;
            f = __half22float2(*(const __half2*)&ra.z); acc[4] += p0 * f.x; acc[5] += p0 * f.y;
            f = __half22float2(*(const __half2*)&ra.w); acc[6] += p0 * f.x; acc[7] += p0 * f.y;
        }
    }
    // ssum: full 64-lane butterfly (inv needed by all lanes)
#pragma unroll
    for (int off = 1; off < 64; off <<= 1)
        ssum += __shfl_xor(ssum, off, 64);

    // ---- fold-reduce acc across the NG row-groups ----
    int chb = cl * 8;
    float v0;
    if constexpr (G == 8) {
        const int b0 = (lane >> 3) & 1, b1 = (lane >> 4) & 1, b2 = (lane >> 5) & 1;
        // off=8 (g bit0): keep 4, send 4
        float s0 = b0 ? acc[0] : acc[4];
        float s1 = b0 ? acc[1] : acc[5];
        float s2 = b0 ? acc[2] : acc[6];
        float s3 = b0 ? acc[3] : acc[7];
        float r0 = __shfl_xor(s0, 8, 64);
        float r1 = __shfl_xor(s1, 8, 64);
        float r2 = __shfl_xor(s2, 8, 64);
        float r3 = __shfl_xor(s3, 8, 64);
        float a0 = (b0 ? acc[4] : acc[0]) + r0;
        float a1 = (b0 ? acc[5] : acc[1]) + r1;
        float a2 = (b0 ? acc[6] : acc[2]) + r2;
        float a3 = (b0 ? acc[7] : acc[3]) + r3;
        // off=16 (g bit1): keep 2, send 2
        float t0 = b1 ? a0 : a2;
        float t1 = b1 ? a1 : a3;
        float q0 = __shfl_xor(t0, 16, 64);
        float q1 = __shfl_xor(t1, 16, 64);
        float c0 = (b1 ? a2 : a0) + q0;
        float c1 = (b1 ? a3 : a1) + q1;
        // off=32 (g bit2): keep 1, send 1
        float u = b2 ? c0 : c1;
        float w = __shfl_xor(u, 32, 64);
        v0 = (b2 ? c1 : c0) + w;
        chb += b0 * 4 + b1 * 2 + b2;
    } else {
        const int b0 = (lane >> 2) & 1, b1 = (lane >> 3) & 1, b2 = (lane >> 4) & 1;
        // off=4 (g bit0)
        float s0 = b0 ? acc[0] : acc[4];
        float s1 = b0 ? acc[1] : acc[5];
        float s2 = b0 ? acc[2] : acc[6];
        float s3 = b0 ? acc[3] : acc[7];
        float r0 = __shfl_xor(s0, 4, 64);
        float r1 = __shfl_xor(s1, 4, 64);
        float r2 = __shfl_xor(s2, 4, 64);
        float r3 = __shfl_xor(s3, 4, 64);
        float a0 = (b0 ? acc[4] : acc[0]) + r0;
        float a1 = (b0 ? acc[5] : acc[1]) + r1;
        float a2 = (b0 ? acc[6] : acc[2]) + r2;
        float a3 = (b0 ? acc[7] : acc[3]) + r3;
        // off=8 (g bit1)
        float t0 = b1 ? a0 : a2;
        float t1 = b1 ? a1 : a3;
        float q0 = __shfl_xor(t0, 8, 64);
        float q1 = __shfl_xor(t1, 8, 64);
        float c0 = (b1 ? a2 : a0) + q0;
        float c1 = (b1 ? a3 : a1) + q1;
        // off=16 (g bit2)
        float u = b2 ? c0 : c1;
        float w = __shfl_xor(u, 16, 64);
        v0 = (b2 ? c1 : c0) + w;
        // off=32 (g bit3): single value, plain exchange-add (both copies identical)
        v0 += __shfl_xor(v0, 32, 64);
        chb += b0 * 4 + b1 * 2 + b2;
    }

    const float inv = 1.f / (ssum + 1e-30f);
    float v = v0 * inv + bias[chb];
    if (ELU) v = (v > 0.f) ? v : expm1f(v);
    if (G == 8 || lane < 32)   // C=32: lanes 32..63 hold duplicate channels
        out[(long long)node * C + chb] = v;
}

extern "C" void kernel_launch(void* const* d_in, const int* in_sizes, int n_in,
                              void* d_out, int out_size, void* d_ws, size_t ws_size,
                              hipStream_t stream) {
    const float* x      = (const float*)d_in[0];
    const void*  edges  = d_in[1];
    const float* W1     = (const float*)d_in[2];
    const float* a_src1 = (const float*)d_in[3];
    const float* a_dst1 = (const float*)d_in[4];
    const float* b1     = (const float*)d_in[5];
    const float* W2     = (const float*)d_in[6];
    const float* a_src2 = (const float*)d_in[7];
    const float* a_dst2 = (const float*)d_in[8];
    const float* b2     = (const float*)d_in[9];

    char* ws = (char*)d_ws;
    size_t off = 0;
    auto alloc = [&](size_t bytes) { char* p = ws + off; off += (bytes + 255) & ~size_t(255); return p; };
    __half*       h1      = (__half*)      alloc((size_t)N_NODES * 64 * 2);  // fp16 H, layer 1
    float*        h2      = (float*)       alloc((size_t)N_NODES * 64 * 4);  // layer-1 out (fp32)
    float*        as1     = (float*)       alloc((size_t)N_NODES * 4);
    float*        ad1     = (float*)       alloc((size_t)N_NODES * 4);
    float*        as2     = (float*)       alloc((size_t)N_NODES * 4);
    float*        ad2     = (float*)       alloc((size_t)N_NODES * 4);
    int*          ghist   = (int*)         alloc((size_t)NBUCK * 4);
    int*          boffs   = (int*)         alloc((size_t)(NBUCK + 1) * 4);
    int*          gcur    = (int*)         alloc((size_t)NBUCK * 4);
    int*          offs    = (int*)         alloc((size_t)(N_NODES + 1) * 4);
    unsigned int* staging = (unsigned int*)alloc((size_t)TOT_E * 4);
    int*          srt     = (int*)         alloc((size_t)(TOT_E + 8) * 4);
    float*        out     = (float*)d_out;
    __half*       g2      = h1;  // h1 dead after k_node<64>; reuse (3.2MB needed < 6.4MB)

    const int NODE_BLOCKS = (N_NODES * 64 + 255) / 256;  // one wave per node

    // binned CSR build front (zero + 416-block atomic histogram: measured-fast form)
    k_zero<<<(NBUCK + 255) / 256, 256, 0, stream>>>(ghist);
    k_binhist<<<416, 256, 0, stream>>>(edges, ghist);
    k_bscan<<<1, 256, 0, stream>>>(ghist, boffs, gcur);
    k_binscatter<<<NCHUNK, 256, 0, stream>>>(edges, gcur, staging);

    // merged: layer-1 GEMM (independent) + bucketsort (needs binscatter) in ONE dispatch;
    // both outputs feed k_node<64>.
    k_sortgemm<<<NGEMM1 + NBUCK, 256, 0, stream>>>(
        staging, boffs, offs, srt, x, W1, a_src1, a_dst1, h1, as1, ad1);
    k_node<64, true><<<NODE_BLOCKS, 256, 0, stream>>>(offs, srt, as1, ad1, h1, b1, h2);

    // layer 2: K=64, N=32, BM=128, BK=32
    k_gemm_att<64, 32, 128, 32><<<(N_NODES + 127) / 128, 256, 0, stream>>>(
        h2, W2, a_src2, a_dst2, g2, as2, ad2);
    k_node<32, false><<<NODE_BLOCKS, 256, 0, stream>>>(offs, srt, as2, ad2, g2, b2, out);
}

// Round 8
// 111.357 us; speedup vs baseline: 1.2933x; 1.0555x over previous
//
#include <hip/hip_runtime.h>
#include <hip/hip_fp16.h>

#define N_NODES 50000
#define N_EDGES 800000
#define TOT_E   (N_EDGES + N_NODES)
#define NEG_SLOPE 0.2f
#define MB_SHIFT 8.0f   // fixed softmax shift: valid upper bound for e=as+ad (|e|<~3);
                        // softmax is shift-invariant so result is exact up to fp rounding.

#define SHIFT  6
#define NBUCK  ((N_NODES + 63) >> SHIFT)       // 782 buckets of 64 nodes
#define NBP    1024                             // padded scan width
#define CHUNK  4096                             // 208 binscatter blocks
#define EPT    (CHUNK / 256)                    // 16 edges per thread
#define NCHUNK ((TOT_E + CHUNK - 1) / CHUNK)
#define NGEMM1 ((N_NODES + 63) / 64)            // 782 GEMM1 blocks (BM=64)

// ---------- edge fetch (handles int32 or int64 edge_index; self-loops appended) ----------
__device__ __forceinline__ void get_edge(const void* edges, int flag64, long long i,
                                         int& src, int& dst) {
    if (i < N_EDGES) {
        if (flag64) {
            const long long* e = (const long long*)edges;
            src = (int)e[i];
            dst = (int)e[N_EDGES + i];
        } else {
            const int* e = (const int*)edges;
            src = e[i];
            dst = e[(long long)N_EDGES + i];
        }
    } else {
        src = dst = (int)(i - N_EDGES);
    }
}

__device__ __forceinline__ int get_dst(const void* edges, int flag64, long long i) {
    if (i < N_EDGES) {
        if (flag64) return (int)((const long long*)edges)[N_EDGES + i];
        return ((const int*)edges)[(long long)N_EDGES + i];
    }
    return (int)(i - N_EDGES);
}

// per-block edge-dtype detection: wave 0 checks first 64 int64 slots, one ballot.
__device__ __forceinline__ int detect64(const void* edges, int tid, int* sfl) {
    if (tid < 64) {
        long long v = ((const long long*)edges)[tid];
        unsigned long long ok = __ballot(v >= 0 && v < N_NODES);
        if (tid == 0) *sfl = (ok == ~0ull) ? 1 : 0;
    }
    __syncthreads();
    return *sfl;
}

// ---------- zero the global bucket histogram (3KB) ----------
__global__ __launch_bounds__(256) void k_zero(int* __restrict__ ghist) {
    int i = blockIdx.x * blockDim.x + threadIdx.x;
    if (i < NBUCK) ghist[i] = 0;
}

// ---------- bucket histogram: 416 blocks, LDS-aggregated, global atomic flush ----------
__global__ __launch_bounds__(256) void k_binhist(const void* edges, int* __restrict__ ghist) {
    __shared__ int h[NBUCK];
    __shared__ int sfl;
    const int tid = threadIdx.x;
    for (int i = tid; i < NBUCK; i += 256) h[i] = 0;
    const int fl = detect64(edges, tid, &sfl);   // includes __syncthreads()
    const int stride = gridDim.x * blockDim.x;
    for (long long i = (long long)blockIdx.x * blockDim.x + tid; i < TOT_E; i += stride)
        atomicAdd(&h[get_dst(edges, fl, i) >> SHIFT], 1);
    __syncthreads();
    for (int i = tid; i < NBUCK; i += 256)
        if (h[i]) atomicAdd(&ghist[i], h[i]);
}

// ---------- single-block scan of bucket histogram -> boffs, gcur ----------
__global__ __launch_bounds__(256) void k_bscan(const int* __restrict__ ghist,
                                               int* __restrict__ boffs,
                                               int* __restrict__ gcur) {
    __shared__ int sc[NBP];
    const int tid = threadIdx.x;
    for (int s = 0; s < 4; s++) {
        int i = tid + s * 256;
        sc[i] = (i < NBUCK) ? ghist[i] : 0;
    }
    __syncthreads();
    for (int off = 1; off < NBP; off <<= 1) {
        int t[4];
        for (int s = 0; s < 4; s++) {
            int a = tid + s * 256;
            t[s] = (a >= off) ? sc[a - off] : 0;
        }
        __syncthreads();
        for (int s = 0; s < 4; s++) sc[tid + s * 256] += t[s];
        __syncthreads();
    }
    for (int s = 0; s < 4; s++) {
        int i = tid + s * 256;
        if (i < NBUCK) {
            int e = sc[i] - ghist[i];   // exclusive
            boffs[i] = e;
            gcur[i]  = e;
        }
    }
    if (tid == 0) boffs[NBUCK] = sc[NBUCK - 1];
}

// ---------- chunked binscatter: group chunk's edges by bucket in LDS, write runs ----------
__global__ __launch_bounds__(256) void k_binscatter(const void* edges,
                                                    int* gcur, unsigned int* staging) {
    __shared__ int sc[NBP];        // counts -> inclusive scan
    __shared__ int so[NBP];        // original counts
    __shared__ int sr[NBUCK];      // running cursor (phase 3)
    __shared__ int gb[NBUCK];      // global base per bucket
    __shared__ unsigned int buf[CHUNK];
    __shared__ int sfl;
    const int tid = threadIdx.x;
    const int c0 = blockIdx.x * CHUNK;
    const int nE = min(CHUNK, TOT_E - c0);
    unsigned int pk[EPT];

    for (int s = 0; s < 4; s++) sc[tid + s * 256] = 0;
    for (int i = tid; i < NBUCK; i += 256) sr[i] = 0;
    const int fl = detect64(edges, tid, &sfl);   // includes __syncthreads()
    // phase 1: read edges, pack, count
#pragma unroll
    for (int j = 0; j < EPT; j++) {
        int li = j * 256 + tid;
        pk[j] = 0u;
        if (li < nE) {
            int src, dst;
            get_edge(edges, fl, (long long)(c0 + li), src, dst);
            pk[j] = ((unsigned int)dst << 16) | (unsigned int)src;
            atomicAdd(&sc[dst >> SHIFT], 1);
        }
    }
    __syncthreads();
    for (int s = 0; s < 4; s++) { int i = tid + s * 256; so[i] = sc[i]; }
    __syncthreads();
    // phase 2: inclusive scan of sc
    for (int off = 1; off < NBP; off <<= 1) {
        int t[4];
        for (int s = 0; s < 4; s++) {
            int a = tid + s * 256;
            t[s] = (a >= off) ? sc[a - off] : 0;
        }
        __syncthreads();
        for (int s = 0; s < 4; s++) sc[tid + s * 256] += t[s];
        __syncthreads();
    }
    // reserve global ranges
    for (int b = tid; b < NBUCK; b += 256)
        if (so[b]) gb[b] = atomicAdd(&gcur[b], so[b]);
    __syncthreads();
    // phase 3: place packed edges bucket-grouped in LDS
#pragma unroll
    for (int j = 0; j < EPT; j++) {
        int li = j * 256 + tid;
        if (li < nE) {
            int b = pk[j] >> (16 + SHIFT);
            int lofs = sc[b] - so[b];
            int pos = lofs + atomicAdd(&sr[b], 1);
            buf[pos] = pk[j];
        }
    }
    __syncthreads();
    // phase 4: write out; consecutive p within a bucket -> consecutive global
    for (int p = tid; p < nE; p += 256) {
        unsigned int e = buf[p];
        int b = e >> (16 + SHIFT);
        int lofs = sc[b] - so[b];
        staging[gb[b] + (p - lofs)] = e;
    }
}

// ---------- merged dispatch: GEMM1 blocks + bucketsort blocks (independent work) ----------
__global__ __launch_bounds__(256) void k_sortgemm(
        const unsigned int* __restrict__ staging, const int* __restrict__ boffs,
        int* __restrict__ offs, int* __restrict__ srt,
        const float* __restrict__ X, const float* __restrict__ W,
        const float* __restrict__ a_src, const float* __restrict__ a_dst,
        __half* __restrict__ H, float* __restrict__ as_, float* __restrict__ ad_) {
    const int tid = threadIdx.x;
    if (blockIdx.x >= NGEMM1) {
        // ----- bucketsort branch -----
        __shared__ int cnt[64];
        __shared__ int base[64];
        __shared__ int cur[64];
        const int b = blockIdx.x - NGEMM1;
        const int node0 = b << SHIFT;
        const int nn = min(64, N_NODES - node0);
        if (tid < 64) cnt[tid] = 0;
        __syncthreads();
        const int beg = boffs[b], end = boffs[b + 1];
        for (int i = beg + tid; i < end; i += 256)
            atomicAdd(&cnt[(staging[i] >> 16) - node0], 1);
        __syncthreads();
        if (tid < 64) {
            int v = cnt[tid];
            int incl = v;
#pragma unroll
            for (int off = 1; off < 64; off <<= 1) {
                int t = __shfl_up(incl, off, 64);
                if (tid >= off) incl += t;
            }
            base[tid] = beg + incl - v;
            cur[tid] = 0;
            if (tid < nn) offs[node0 + tid] = beg + incl - v;
        }
        __syncthreads();
        for (int i = beg + tid; i < end; i += 256) {
            unsigned int e = staging[i];
            int dl = (int)(e >> 16) - node0;
            int pos = base[dl] + atomicAdd(&cur[dl], 1);
            srt[pos] = (int)(e & 0xFFFFu);
        }
        if (b == 0 && tid == 0) offs[N_NODES] = boffs[NBUCK];
        return;
    }
    // ----- GEMM1 branch: K=128, N=64, BM=64, BK=32 -----
    constexpr int K = 128, N = 64, BM = 64, BK = 32;
    constexpr int TCOLS = N / 4;                 // 16
    constexpr int KPT = (BM * BK) / 256;         // 8
    __shared__ float Xs[BK][BM];
    __shared__ float Ws[BK][N];
    const int bid  = blockIdx.x;
    const int tcol = tid % TCOLS;
    const int trow = tid / TCOLS;
    const int node0 = bid * BM;
    const int r0 = trow * 4;
    const int c0 = tcol * 4;
    float acc[4][4] = {};

    const int sm = tid % BM;
    const int skb = (tid / BM) * KPT;
    const int srow = (node0 + sm < N_NODES) ? (node0 + sm) : (N_NODES - 1);

    for (int k0 = 0; k0 < K; k0 += BK) {
        const float* xp = X + (long long)srow * K + k0 + skb;
#pragma unroll
        for (int j = 0; j < KPT; j += 4) {
            float4 v = *(const float4*)(xp + j);
            Xs[skb + j + 0][sm] = v.x;
            Xs[skb + j + 1][sm] = v.y;
            Xs[skb + j + 2][sm] = v.z;
            Xs[skb + j + 3][sm] = v.w;
        }
#pragma unroll
        for (int i = tid; i < BK * N / 4; i += 256)
            ((float4*)Ws)[i] = ((const float4*)W)[(k0 * N) / 4 + i];
        __syncthreads();
#pragma unroll 8
        for (int k = 0; k < BK; ++k) {
            float4 xa = *(const float4*)&Xs[k][r0];
            float4 wb = *(const float4*)&Ws[k][c0];
            float xr[4] = {xa.x, xa.y, xa.z, xa.w};
            float wc[4] = {wb.x, wb.y, wb.z, wb.w};
#pragma unroll
            for (int i = 0; i < 4; ++i)
#pragma unroll
                for (int j = 0; j < 4; ++j)
                    acc[i][j] += xr[i] * wc[j];
        }
        __syncthreads();
    }

    const float4 asv = *(const float4*)(a_src + c0);
    const float4 adv = *(const float4*)(a_dst + c0);
    const int rbase = node0 + r0;
    float vsr[4], vdr[4];
#pragma unroll
    for (int i = 0; i < 4; ++i) {
        float vs = acc[i][0] * asv.x + acc[i][1] * asv.y + acc[i][2] * asv.z + acc[i][3] * asv.w;
        float vd = acc[i][0] * adv.x + acc[i][1] * adv.y + acc[i][2] * adv.z + acc[i][3] * adv.w;
#pragma unroll
        for (int off = 1; off < TCOLS; off <<= 1) {
            vs += __shfl_xor(vs, off, 64);
            vd += __shfl_xor(vd, off, 64);
        }
        vsr[i] = vs; vdr[i] = vd;
        if (rbase + i < N_NODES) {
            __half2 q0 = __floats2half2_rn(acc[i][0], acc[i][1]);
            __half2 q1 = __floats2half2_rn(acc[i][2], acc[i][3]);
            uint2 raw;
            raw.x = *(unsigned int*)&q0;
            raw.y = *(unsigned int*)&q1;
            *(uint2*)(H + (long long)(rbase + i) * N + c0) = raw;
        }
    }
    if (tcol == 0) {
#pragma unroll
        for (int i = 0; i < 4; ++i) {
            if (rbase + i < N_NODES) {
                as_[rbase + i] = vsr[i];
                ad_[rbase + i] = vdr[i];
            }
        }
    }
}

// ---------- register-tiled GEMM (H = X @ W, stored fp16) + attention dots (layer 2) ----------
template<int K, int N, int BM, int BK>
__global__ __launch_bounds__(256) void k_gemm_att(
        const float* __restrict__ X, const float* __restrict__ W,
        const float* __restrict__ a_src, const float* __restrict__ a_dst,
        __half* __restrict__ H, float* __restrict__ as_, float* __restrict__ ad_) {
    constexpr int TCOLS = N / 4;
    __shared__ float Xs[BK][BM];
    __shared__ float Ws[BK][N];
    const int tid  = threadIdx.x;
    const int tcol = tid % TCOLS;
    const int trow = tid / TCOLS;
    const int node0 = blockIdx.x * BM;
    const int r0 = trow * 4;
    const int c0 = tcol * 4;
    float acc[4][4] = {};

    constexpr int KPT = (BM * BK) / 256;
    const int sm = tid % BM;
    const int skb = (tid / BM) * KPT;
    const int srow = (node0 + sm < N_NODES) ? (node0 + sm) : (N_NODES - 1);

    for (int k0 = 0; k0 < K; k0 += BK) {
        const float* xp = X + (long long)srow * K + k0 + skb;
#pragma unroll
        for (int j = 0; j < KPT; j += 4) {
            float4 v = *(const float4*)(xp + j);
            Xs[skb + j + 0][sm] = v.x;
            Xs[skb + j + 1][sm] = v.y;
            Xs[skb + j + 2][sm] = v.z;
            Xs[skb + j + 3][sm] = v.w;
        }
#pragma unroll
        for (int i = tid; i < BK * N / 4; i += 256)
            ((float4*)Ws)[i] = ((const float4*)W)[(k0 * N) / 4 + i];
        __syncthreads();
#pragma unroll 8
        for (int k = 0; k < BK; ++k) {
            float4 xa = *(const float4*)&Xs[k][r0];
            float4 wb = *(const float4*)&Ws[k][c0];
            float xr[4] = {xa.x, xa.y, xa.z, xa.w};
            float wc[4] = {wb.x, wb.y, wb.z, wb.w};
#pragma unroll
            for (int i = 0; i < 4; ++i)
#pragma unroll
                for (int j = 0; j < 4; ++j)
                    acc[i][j] += xr[i] * wc[j];
        }
        __syncthreads();
    }

    const float4 asv = *(const float4*)(a_src + c0);
    const float4 adv = *(const float4*)(a_dst + c0);
    const int rbase = node0 + r0;
    float vsr[4], vdr[4];
#pragma unroll
    for (int i = 0; i < 4; ++i) {
        float vs = acc[i][0] * asv.x + acc[i][1] * asv.y + acc[i][2] * asv.z + acc[i][3] * asv.w;
        float vd = acc[i][0] * adv.x + acc[i][1] * adv.y + acc[i][2] * adv.z + acc[i][3] * adv.w;
#pragma unroll
        for (int off = 1; off < TCOLS; off <<= 1) {
            vs += __shfl_xor(vs, off, 64);
            vd += __shfl_xor(vd, off, 64);
        }
        vsr[i] = vs; vdr[i] = vd;
        if (rbase + i < N_NODES) {
            __half2 q0 = __floats2half2_rn(acc[i][0], acc[i][1]);
            __half2 q1 = __floats2half2_rn(acc[i][2], acc[i][3]);
            uint2 raw;
            raw.x = *(unsigned int*)&q0;
            raw.y = *(unsigned int*)&q1;
            *(uint2*)(H + (long long)(rbase + i) * N + c0) = raw;
        }
    }
    if (tcol == 0) {
#pragma unroll
        for (int i = 0; i < 4; ++i) {
            if (rbase + i < N_NODES) {
                as_[rbase + i] = vsr[i];
                ad_[rbase + i] = vdr[i];
            }
        }
    }
}

// ---------- fused per-node pass: TWO NODES PER WAVE (one per 32-lane half) ----------
// Confirmed (r6/r7): k_node is bound by per-wave serial work + DS-pipe ops, not memory.
// node = 2*wid + (lane>=32). All control flow is wave-uniform (mdeg/mnb = max over the
// two halves; inactive slots carry p=0 -> benign row-0 loads). Width-32 shuffles are
// segment-local, so one instruction stream serves both nodes.
// Fold-reduce within each half: C=64 -> 2 steps (lane owns 2 adjacent channels, float2
// store, all 64 lanes active); C=32 -> 3 steps (1 channel/lane, all lanes active).
template<int C, bool ELU>
__global__ __launch_bounds__(256) void k_node(
        const int* __restrict__ offs, const int* __restrict__ srt,
        const float* __restrict__ as_, const float* __restrict__ ad_,
        const __half* __restrict__ H, const float* __restrict__ bias,
        float* __restrict__ out) {
    constexpr int G  = C / 8;     // lanes per row (8 for C=64, 4 for C=32)
    constexpr int NR = 32 / G;    // rows per slot per node (4 or 8)
    const int wid = (int)(((long long)blockIdx.x * blockDim.x + threadIdx.x) >> 6);
    if (wid * 2 >= N_NODES) return;
    const int lane = threadIdx.x & 63;
    const int ln   = lane & 31;                  // lane within half
    const int node = wid * 2 + (lane >> 5);
    const bool nv = node < N_NODES;
    const int beg = nv ? offs[node] : 0;
    const int end = nv ? offs[node + 1] : 0;
    const int deg = end - beg;
    const int mdeg = max(deg, __shfl_xor(deg, 32, 64));   // wave-uniform outer bound
    const float adn = nv ? ad_[node] : 0.f;
    const int g  = ln / G;
    const int cl = ln % G;
    float acc[8] = {};
    float ssum = 0.f;

    for (int base = 0; base < mdeg; base += 32) {
        const int nb  = min(32, deg - base);     // per-half (may be <=0)
        const int mnb = min(32, mdeg - base);    // wave-uniform inner bound
        // ---- phase A: one edge per lane (32 per node) ----
        int s = 0;
        float p = 0.f;
        if (ln < nb) {
            s = srt[beg + base + ln];
            float e = as_[s] + adn;
            e = (e > 0.f) ? e : NEG_SLOPE * e;
            p = __expf(e - MB_SHIFT);
        }
        ssum += p;
        // ---- phase B: width-32 broadcasts; slots past own nb carry p=0 ----
        int j = 0;
        for (; j + NR < mnb; j += 2 * NR) {
            const int i0 = j + g, i1 = j + NR + g;
            const int   s0 = __shfl(s, i0, 32);
            const int   s1 = __shfl(s, i1, 32);
            const float p0 = __shfl(p, i0, 32);
            const float p1 = __shfl(p, i1, 32);
            const uint4 ra = *(const uint4*)(H + (long long)s0 * C + cl * 8);
            const uint4 rb = *(const uint4*)(H + (long long)s1 * C + cl * 8);
            float2 f;
            f = __half22float2(*(const __half2*)&ra.x); acc[0] += p0 * f.x; acc[1] += p0 * f.y;
            f = __half22float2(*(const __half2*)&ra.y); acc[2] += p0 * f.x; acc[3] += p0 * f.y;
            f = __half22float2(*(const __half2*)&ra.z); acc[4] += p0 * f.x; acc[5] += p0 * f.y;
            f = __half22float2(*(const __half2*)&ra.w); acc[6] += p0 * f.x; acc[7] += p0 * f.y;
            f = __half22float2(*(const __half2*)&rb.x); acc[0] += p1 * f.x; acc[1] += p1 * f.y;
            f = __half22float2(*(const __half2*)&rb.y); acc[2] += p1 * f.x; acc[3] += p1 * f.y;
            f = __half22float2(*(const __half2*)&rb.z); acc[4] += p1 * f.x; acc[5] += p1 * f.y;
            f = __half22float2(*(const __half2*)&rb.w); acc[6] += p1 * f.x; acc[7] += p1 * f.y;
        }
        if (j < mnb) {
            const int i0 = j + g;
            const int   s0 = __shfl(s, i0, 32);
            const float p0 = __shfl(p, i0, 32);
            const uint4 ra = *(const uint4*)(H + (long long)s0 * C + cl * 8);
            float2 f;
            f = __half22float2(*(const __half2*)&ra.x); acc[0] += p0 * f.x; acc[1] += p0 * f.y;
            f = __half22float2(*(const __half2*)&ra.y); acc[2] += p0 * f.x; acc[3] += p0 * f.y;
            f = __half22float2(*(const __half2*)&ra.z); acc[4] += p0 * f.x; acc[5] += p0 * f.y;
            f = __half22float2(*(const __half2*)&ra.w); acc[6] += p0 * f.x; acc[7] += p0 * f.y;
        }
    }
    // ssum: butterfly within each half (offsets 1..16 never cross the 32-boundary)
#pragma unroll
    for (int off = 1; off < 32; off <<= 1)
        ssum += __shfl_xor(ssum, off, 64);
    const float inv = 1.f / (ssum + 1e-30f);

    if constexpr (G == 8) {
        // C=64: 4 row-groups per half -> 2 fold steps; lane owns 2 adjacent channels.
        const int b0 = (ln >> 3) & 1, b1 = (ln >> 4) & 1;
        // xor 8 (group bit0): send discarded 4, keep 4
        float s0 = b0 ? acc[0] : acc[4];
        float s1 = b0 ? acc[1] : acc[5];
        float s2 = b0 ? acc[2] : acc[6];
        float s3 = b0 ? acc[3] : acc[7];
        float r0 = __shfl_xor(s0, 8, 64);
        float r1 = __shfl_xor(s1, 8, 64);
        float r2 = __shfl_xor(s2, 8, 64);
        float r3 = __shfl_xor(s3, 8, 64);
        float a0 = (b0 ? acc[4] : acc[0]) + r0;
        float a1 = (b0 ? acc[5] : acc[1]) + r1;
        float a2 = (b0 ? acc[6] : acc[2]) + r2;
        float a3 = (b0 ? acc[7] : acc[3]) + r3;
        // xor 16 (group bit1): send 2, keep 2
        float t0 = b1 ? a0 : a2;
        float t1 = b1 ? a1 : a3;
        float q0 = __shfl_xor(t0, 16, 64);
        float q1 = __shfl_xor(t1, 16, 64);
        float c0 = (b1 ? a2 : a0) + q0;
        float c1 = (b1 ? a3 : a1) + q1;
        const int ch = cl * 8 + b0 * 4 + b1 * 2;
        if (nv) {
            float v0 = c0 * inv + bias[ch];
            float v1 = c1 * inv + bias[ch + 1];
            if (ELU) {
                v0 = (v0 > 0.f) ? v0 : expm1f(v0);
                v1 = (v1 > 0.f) ? v1 : expm1f(v1);
            }
            float2 v = {v0, v1};
            *(float2*)(out + (long long)node * C + ch) = v;
        }
    } else {
        // C=32: 8 row-groups per half -> 3 fold steps; lane owns 1 channel.
        const int b0 = (ln >> 2) & 1, b1 = (ln >> 3) & 1, b2 = (ln >> 4) & 1;
        // xor 4 (group bit0)
        float s0 = b0 ? acc[0] : acc[4];
        float s1 = b0 ? acc[1] : acc[5];
        float s2 = b0 ? acc[2] : acc[6];
        float s3 = b0 ? acc[3] : acc[7];
        float r0 = __shfl_xor(s0, 4, 64);
        float r1 = __shfl_xor(s1, 4, 64);
        float r2 = __shfl_xor(s2, 4, 64);
        float r3 = __shfl_xor(s3, 4, 64);
        float a0 = (b0 ? acc[4] : acc[0]) + r0;
        float a1 = (b0 ? acc[5] : acc[1]) + r1;
        float a2 = (b0 ? acc[6] : acc[2]) + r2;
        float a3 = (b0 ? acc[7] : acc[3]) + r3;
        // xor 8 (group bit1)
        float t0 = b1 ? a0 : a2;
        float t1 = b1 ? a1 : a3;
        float q0 = __shfl_xor(t0, 8, 64);
        float q1 = __shfl_xor(t1, 8, 64);
        float c0 = (b1 ? a2 : a0) + q0;
        float c1 = (b1 ? a3 : a1) + q1;
        // xor 16 (group bit2)
        float u = b2 ? c0 : c1;
        float w = __shfl_xor(u, 16, 64);
        float v0 = (b2 ? c1 : c0) + w;
        const int ch = cl * 8 + b0 * 4 + b1 * 2 + b2;
        if (nv) {
            float v = v0 * inv + bias[ch];
            if (ELU) v = (v > 0.f) ? v : expm1f(v);
            out[(long long)node * C + ch] = v;
        }
    }
}

extern "C" void kernel_launch(void* const* d_in, const int* in_sizes, int n_in,
                              void* d_out, int out_size, void* d_ws, size_t ws_size,
                              hipStream_t stream) {
    const float* x      = (const float*)d_in[0];
    const void*  edges  = d_in[1];
    const float* W1     = (const float*)d_in[2];
    const float* a_src1 = (const float*)d_in[3];
    const float* a_dst1 = (const float*)d_in[4];
    const float* b1     = (const float*)d_in[5];
    const float* W2     = (const float*)d_in[6];
    const float* a_src2 = (const float*)d_in[7];
    const float* a_dst2 = (const float*)d_in[8];
    const float* b2     = (const float*)d_in[9];

    char* ws = (char*)d_ws;
    size_t off = 0;
    auto alloc = [&](size_t bytes) { char* p = ws + off; off += (bytes + 255) & ~size_t(255); return p; };
    __half*       h1      = (__half*)      alloc((size_t)N_NODES * 64 * 2);  // fp16 H, layer 1
    float*        h2      = (float*)       alloc((size_t)N_NODES * 64 * 4);  // layer-1 out (fp32)
    float*        as1     = (float*)       alloc((size_t)N_NODES * 4);
    float*        ad1     = (float*)       alloc((size_t)N_NODES * 4);
    float*        as2     = (float*)       alloc((size_t)N_NODES * 4);
    float*        ad2     = (float*)       alloc((size_t)N_NODES * 4);
    int*          ghist   = (int*)         alloc((size_t)NBUCK * 4);
    int*          boffs   = (int*)         alloc((size_t)(NBUCK + 1) * 4);
    int*          gcur    = (int*)         alloc((size_t)NBUCK * 4);
    int*          offs    = (int*)         alloc((size_t)(N_NODES + 1) * 4);
    unsigned int* staging = (unsigned int*)alloc((size_t)TOT_E * 4);
    int*          srt     = (int*)         alloc((size_t)(TOT_E + 8) * 4);
    float*        out     = (float*)d_out;
    __half*       g2      = h1;  // h1 dead after k_node<64>; reuse (3.2MB needed < 6.4MB)

    // two nodes per wave
    const int NODE_BLOCKS = (((N_NODES + 1) / 2) * 64 + 255) / 256;

    // binned CSR build front (zero + 416-block atomic histogram: measured-fast form)
    k_zero<<<(NBUCK + 255) / 256, 256, 0, stream>>>(ghist);
    k_binhist<<<416, 256, 0, stream>>>(edges, ghist);
    k_bscan<<<1, 256, 0, stream>>>(ghist, boffs, gcur);
    k_binscatter<<<NCHUNK, 256, 0, stream>>>(edges, gcur, staging);

    // merged: layer-1 GEMM (independent) + bucketsort (needs binscatter) in ONE dispatch;
    // both outputs feed k_node<64>.
    k_sortgemm<<<NGEMM1 + NBUCK, 256, 0, stream>>>(
        staging, boffs, offs, srt, x, W1, a_src1, a_dst1, h1, as1, ad1);
    k_node<64, true><<<NODE_BLOCKS, 256, 0, stream>>>(offs, srt, as1, ad1, h1, b1, h2);

    // layer 2: K=64, N=32, BM=128, BK=32
    k_gemm_att<64, 32, 128, 32><<<(N_NODES + 127) / 128, 256, 0, stream>>>(
        h2, W2, a_src2, a_dst2, g2, as2, ad2);
    k_node<32, false><<<NODE_BLOCKS, 256, 0, stream>>>(offs, srt, as2, ad2, g2, b2, out);
}

// Round 9
// 110.388 us; speedup vs baseline: 1.3046x; 1.0088x over previous
//
#include <hip/hip_runtime.h>
#include <hip/hip_fp16.h>

#define N_NODES 50000
#define N_EDGES 800000
#define TOT_E   (N_EDGES + N_NODES)
#define NEG_SLOPE 0.2f
#define MB_SHIFT 8.0f   // fixed softmax shift: valid upper bound for e=as+ad (|e|<~3);
                        // softmax is shift-invariant so result is exact up to fp rounding.

#define SHIFT  6
#define NBUCK  ((N_NODES + 63) >> SHIFT)       // 782 buckets of 64 nodes
#define NBP    1024                             // padded scan width
#define CHUNK  4096                             // 208 binscatter blocks
#define EPT    (CHUNK / 256)                    // 16 edges per thread
#define NCHUNK ((TOT_E + CHUNK - 1) / CHUNK)
#define NGEMM1 ((N_NODES + 63) / 64)            // 782 GEMM1 blocks (BM=64)

// ---------- edge fetch (handles int32 or int64 edge_index; self-loops appended) ----------
__device__ __forceinline__ void get_edge(const void* edges, int flag64, long long i,
                                         int& src, int& dst) {
    if (i < N_EDGES) {
        if (flag64) {
            const long long* e = (const long long*)edges;
            src = (int)e[i];
            dst = (int)e[N_EDGES + i];
        } else {
            const int* e = (const int*)edges;
            src = e[i];
            dst = e[(long long)N_EDGES + i];
        }
    } else {
        src = dst = (int)(i - N_EDGES);
    }
}

__device__ __forceinline__ int get_dst(const void* edges, int flag64, long long i) {
    if (i < N_EDGES) {
        if (flag64) return (int)((const long long*)edges)[N_EDGES + i];
        return ((const int*)edges)[(long long)N_EDGES + i];
    }
    return (int)(i - N_EDGES);
}

// per-block edge-dtype detection: wave 0 checks first 64 int64 slots, one ballot.
__device__ __forceinline__ int detect64(const void* edges, int tid, int* sfl) {
    if (tid < 64) {
        long long v = ((const long long*)edges)[tid];
        unsigned long long ok = __ballot(v >= 0 && v < N_NODES);
        if (tid == 0) *sfl = (ok == ~0ull) ? 1 : 0;
    }
    __syncthreads();
    return *sfl;
}

// ---------- zero the global bucket histogram (3KB) ----------
__global__ __launch_bounds__(256) void k_zero(int* __restrict__ ghist) {
    int i = blockIdx.x * blockDim.x + threadIdx.x;
    if (i < NBUCK) ghist[i] = 0;
}

// ---------- bucket histogram: 416 blocks, LDS-aggregated, global atomic flush ----------
__global__ __launch_bounds__(256) void k_binhist(const void* edges, int* __restrict__ ghist) {
    __shared__ int h[NBUCK];
    __shared__ int sfl;
    const int tid = threadIdx.x;
    for (int i = tid; i < NBUCK; i += 256) h[i] = 0;
    const int fl = detect64(edges, tid, &sfl);   // includes __syncthreads()
    const int stride = gridDim.x * blockDim.x;
    for (long long i = (long long)blockIdx.x * blockDim.x + tid; i < TOT_E; i += stride)
        atomicAdd(&h[get_dst(edges, fl, i) >> SHIFT], 1);
    __syncthreads();
    for (int i = tid; i < NBUCK; i += 256)
        if (h[i]) atomicAdd(&ghist[i], h[i]);
}

// ---------- single-block scan of bucket histogram -> boffs, gcur ----------
__global__ __launch_bounds__(256) void k_bscan(const int* __restrict__ ghist,
                                               int* __restrict__ boffs,
                                               int* __restrict__ gcur) {
    __shared__ int sc[NBP];
    const int tid = threadIdx.x;
    for (int s = 0; s < 4; s++) {
        int i = tid + s * 256;
        sc[i] = (i < NBUCK) ? ghist[i] : 0;
    }
    __syncthreads();
    for (int off = 1; off < NBP; off <<= 1) {
        int t[4];
        for (int s = 0; s < 4; s++) {
            int a = tid + s * 256;
            t[s] = (a >= off) ? sc[a - off] : 0;
        }
        __syncthreads();
        for (int s = 0; s < 4; s++) sc[tid + s * 256] += t[s];
        __syncthreads();
    }
    for (int s = 0; s < 4; s++) {
        int i = tid + s * 256;
        if (i < NBUCK) {
            int e = sc[i] - ghist[i];   // exclusive
            boffs[i] = e;
            gcur[i]  = e;
        }
    }
    if (tid == 0) boffs[NBUCK] = sc[NBUCK - 1];
}

// ---------- chunked binscatter: group chunk's edges by bucket in LDS, write runs ----------
__global__ __launch_bounds__(256) void k_binscatter(const void* edges,
                                                    int* gcur, unsigned int* staging) {
    __shared__ int sc[NBP];        // counts -> inclusive scan
    __shared__ int so[NBP];        // original counts
    __shared__ int sr[NBUCK];      // running cursor (phase 3)
    __shared__ int gb[NBUCK];      // global base per bucket
    __shared__ unsigned int buf[CHUNK];
    __shared__ int sfl;
    const int tid = threadIdx.x;
    const int c0 = blockIdx.x * CHUNK;
    const int nE = min(CHUNK, TOT_E - c0);
    unsigned int pk[EPT];

    for (int s = 0; s < 4; s++) sc[tid + s * 256] = 0;
    for (int i = tid; i < NBUCK; i += 256) sr[i] = 0;
    const int fl = detect64(edges, tid, &sfl);   // includes __syncthreads()
    // phase 1: read edges, pack, count
#pragma unroll
    for (int j = 0; j < EPT; j++) {
        int li = j * 256 + tid;
        pk[j] = 0u;
        if (li < nE) {
            int src, dst;
            get_edge(edges, fl, (long long)(c0 + li), src, dst);
            pk[j] = ((unsigned int)dst << 16) | (unsigned int)src;
            atomicAdd(&sc[dst >> SHIFT], 1);
        }
    }
    __syncthreads();
    for (int s = 0; s < 4; s++) { int i = tid + s * 256; so[i] = sc[i]; }
    __syncthreads();
    // phase 2: inclusive scan of sc
    for (int off = 1; off < NBP; off <<= 1) {
        int t[4];
        for (int s = 0; s < 4; s++) {
            int a = tid + s * 256;
            t[s] = (a >= off) ? sc[a - off] : 0;
        }
        __syncthreads();
        for (int s = 0; s < 4; s++) sc[tid + s * 256] += t[s];
        __syncthreads();
    }
    // reserve global ranges
    for (int b = tid; b < NBUCK; b += 256)
        if (so[b]) gb[b] = atomicAdd(&gcur[b], so[b]);
    __syncthreads();
    // phase 3: place packed edges bucket-grouped in LDS
#pragma unroll
    for (int j = 0; j < EPT; j++) {
        int li = j * 256 + tid;
        if (li < nE) {
            int b = pk[j] >> (16 + SHIFT);
            int lofs = sc[b] - so[b];
            int pos = lofs + atomicAdd(&sr[b], 1);
            buf[pos] = pk[j];
        }
    }
    __syncthreads();
    // phase 4: write out; consecutive p within a bucket -> consecutive global
    for (int p = tid; p < nE; p += 256) {
        unsigned int e = buf[p];
        int b = e >> (16 + SHIFT);
        int lofs = sc[b] - so[b];
        staging[gb[b] + (p - lofs)] = e;
    }
}

// ---------- merged dispatch: GEMM1 blocks + bucketsort blocks (independent work) ----------
__global__ __launch_bounds__(256) void k_sortgemm(
        const unsigned int* __restrict__ staging, const int* __restrict__ boffs,
        int* __restrict__ offs, int* __restrict__ srt,
        const float* __restrict__ X, const float* __restrict__ W,
        const float* __restrict__ a_src, const float* __restrict__ a_dst,
        __half* __restrict__ H, float* __restrict__ as_, float* __restrict__ ad_) {
    const int tid = threadIdx.x;
    if (blockIdx.x >= NGEMM1) {
        // ----- bucketsort branch -----
        __shared__ int cnt[64];
        __shared__ int base[64];
        __shared__ int cur[64];
        const int b = blockIdx.x - NGEMM1;
        const int node0 = b << SHIFT;
        const int nn = min(64, N_NODES - node0);
        if (tid < 64) cnt[tid] = 0;
        __syncthreads();
        const int beg = boffs[b], end = boffs[b + 1];
        for (int i = beg + tid; i < end; i += 256)
            atomicAdd(&cnt[(staging[i] >> 16) - node0], 1);
        __syncthreads();
        if (tid < 64) {
            int v = cnt[tid];
            int incl = v;
#pragma unroll
            for (int off = 1; off < 64; off <<= 1) {
                int t = __shfl_up(incl, off, 64);
                if (tid >= off) incl += t;
            }
            base[tid] = beg + incl - v;
            cur[tid] = 0;
            if (tid < nn) offs[node0 + tid] = beg + incl - v;
        }
        __syncthreads();
        for (int i = beg + tid; i < end; i += 256) {
            unsigned int e = staging[i];
            int dl = (int)(e >> 16) - node0;
            int pos = base[dl] + atomicAdd(&cur[dl], 1);
            srt[pos] = (int)(e & 0xFFFFu);
        }
        if (b == 0 && tid == 0) offs[N_NODES] = boffs[NBUCK];
        return;
    }
    // ----- GEMM1 branch: K=128, N=64, BM=64, BK=32 -----
    constexpr int K = 128, N = 64, BM = 64, BK = 32;
    constexpr int TCOLS = N / 4;                 // 16
    constexpr int KPT = (BM * BK) / 256;         // 8
    __shared__ float Xs[BK][BM];
    __shared__ float Ws[BK][N];
    const int bid  = blockIdx.x;
    const int tcol = tid % TCOLS;
    const int trow = tid / TCOLS;
    const int node0 = bid * BM;
    const int r0 = trow * 4;
    const int c0 = tcol * 4;
    float acc[4][4] = {};

    const int sm = tid % BM;
    const int skb = (tid / BM) * KPT;
    const int srow = (node0 + sm < N_NODES) ? (node0 + sm) : (N_NODES - 1);

    for (int k0 = 0; k0 < K; k0 += BK) {
        const float* xp = X + (long long)srow * K + k0 + skb;
#pragma unroll
        for (int j = 0; j < KPT; j += 4) {
            float4 v = *(const float4*)(xp + j);
            Xs[skb + j + 0][sm] = v.x;
            Xs[skb + j + 1][sm] = v.y;
            Xs[skb + j + 2][sm] = v.z;
            Xs[skb + j + 3][sm] = v.w;
        }
#pragma unroll
        for (int i = tid; i < BK * N / 4; i += 256)
            ((float4*)Ws)[i] = ((const float4*)W)[(k0 * N) / 4 + i];
        __syncthreads();
#pragma unroll 8
        for (int k = 0; k < BK; ++k) {
            float4 xa = *(const float4*)&Xs[k][r0];
            float4 wb = *(const float4*)&Ws[k][c0];
            float xr[4] = {xa.x, xa.y, xa.z, xa.w};
            float wc[4] = {wb.x, wb.y, wb.z, wb.w};
#pragma unroll
            for (int i = 0; i < 4; ++i)
#pragma unroll
                for (int j = 0; j < 4; ++j)
                    acc[i][j] += xr[i] * wc[j];
        }
        __syncthreads();
    }

    const float4 asv = *(const float4*)(a_src + c0);
    const float4 adv = *(const float4*)(a_dst + c0);
    const int rbase = node0 + r0;
    float vsr[4], vdr[4];
#pragma unroll
    for (int i = 0; i < 4; ++i) {
        float vs = acc[i][0] * asv.x + acc[i][1] * asv.y + acc[i][2] * asv.z + acc[i][3] * asv.w;
        float vd = acc[i][0] * adv.x + acc[i][1] * adv.y + acc[i][2] * adv.z + acc[i][3] * adv.w;
#pragma unroll
        for (int off = 1; off < TCOLS; off <<= 1) {
            vs += __shfl_xor(vs, off, 64);
            vd += __shfl_xor(vd, off, 64);
        }
        vsr[i] = vs; vdr[i] = vd;
        if (rbase + i < N_NODES) {
            __half2 q0 = __floats2half2_rn(acc[i][0], acc[i][1]);
            __half2 q1 = __floats2half2_rn(acc[i][2], acc[i][3]);
            uint2 raw;
            raw.x = *(unsigned int*)&q0;
            raw.y = *(unsigned int*)&q1;
            *(uint2*)(H + (long long)(rbase + i) * N + c0) = raw;
        }
    }
    if (tcol == 0) {
#pragma unroll
        for (int i = 0; i < 4; ++i) {
            if (rbase + i < N_NODES) {
                as_[rbase + i] = vsr[i];
                ad_[rbase + i] = vdr[i];
            }
        }
    }
}

// ---------- layer-1 node pass, TWO NODES PER WAVE, with FUSED layer-2 GEMM ----------
// Same aggregation structure as round-8 (confirmed DS/overhead-bound). New epilogue:
// after fold-reduce each half-wave holds its node's 64-ch h2 row (2 ch/lane). The
// layer-2 GEMM is per-node-row (h2row @ W2 -> 32 outs), so it fuses here:
//   1) float2 ds_write of (v0,v1) to a WAVE-PRIVATE LDS slice (intra-wave DS ordering
//      -> no barrier needed; no cross-wave sharing).
//   2) lane ln computes y[ln] = sum_ch hrow[ch]*W2[ch][ln]: 16 broadcast ds_read_b128
//      + 64 L1-hot coalesced W2 loads + 64 FMAs.
//   3) as2/ad2 att dots: 1 mult + 5 within-half shfls each; lane 0 writes scalars.
//   4) y -> fp16 g2 (same rounding as the old gemm epilogue).
// Removes the entire layer-2 GEMM dispatch + 25.6MB of h2 round-trip traffic.
__global__ __launch_bounds__(256) void k_node1(
        const int* __restrict__ offs, const int* __restrict__ srt,
        const float* __restrict__ as_, const float* __restrict__ ad_,
        const __half* __restrict__ H, const float* __restrict__ bias,
        const float* __restrict__ W2, const float* __restrict__ a_src2,
        const float* __restrict__ a_dst2,
        __half* __restrict__ g2, float* __restrict__ as2, float* __restrict__ ad2) {
    constexpr int C = 64, G = 8, NR = 4;   // G lanes/row, NR rows per slot per node
    __shared__ float hrow[4][2][64];       // [wave-in-block][half][channel]
    const int wid = (int)(((long long)blockIdx.x * blockDim.x + threadIdx.x) >> 6);
    if (wid * 2 >= N_NODES) return;
    const int lane = threadIdx.x & 63;
    const int ln   = lane & 31;
    const int node = wid * 2 + (lane >> 5);
    const bool nv = node < N_NODES;
    const int beg = nv ? offs[node] : 0;
    const int end = nv ? offs[node + 1] : 0;
    const int deg = end - beg;
    const int mdeg = max(deg, __shfl_xor(deg, 32, 64));
    const float adn = nv ? ad_[node] : 0.f;
    const int g  = ln / G;
    const int cl = ln % G;
    float acc[8] = {};
    float ssum = 0.f;

    for (int base = 0; base < mdeg; base += 32) {
        const int nb  = min(32, deg - base);
        const int mnb = min(32, mdeg - base);
        // ---- phase A ----
        int s = 0;
        float p = 0.f;
        if (ln < nb) {
            s = srt[beg + base + ln];
            float e = as_[s] + adn;
            e = (e > 0.f) ? e : NEG_SLOPE * e;
            p = __expf(e - MB_SHIFT);
        }
        ssum += p;
        // ---- phase B ----
        int j = 0;
        for (; j + NR < mnb; j += 2 * NR) {
            const int i0 = j + g, i1 = j + NR + g;
            const int   s0 = __shfl(s, i0, 32);
            const int   s1 = __shfl(s, i1, 32);
            const float p0 = __shfl(p, i0, 32);
            const float p1 = __shfl(p, i1, 32);
            const uint4 ra = *(const uint4*)(H + (long long)s0 * C + cl * 8);
            const uint4 rb = *(const uint4*)(H + (long long)s1 * C + cl * 8);
            float2 f;
            f = __half22float2(*(const __half2*)&ra.x); acc[0] += p0 * f.x; acc[1] += p0 * f.y;
            f = __half22float2(*(const __half2*)&ra.y); acc[2] += p0 * f.x; acc[3] += p0 * f.y;
            f = __half22float2(*(const __half2*)&ra.z); acc[4] += p0 * f.x; acc[5] += p0 * f.y;
            f = __half22float2(*(const __half2*)&ra.w); acc[6] += p0 * f.x; acc[7] += p0 * f.y;
            f = __half22float2(*(const __half2*)&rb.x); acc[0] += p1 * f.x; acc[1] += p1 * f.y;
            f = __half22float2(*(const __half2*)&rb.y); acc[2] += p1 * f.x; acc[3] += p1 * f.y;
            f = __half22float2(*(const __half2*)&rb.z); acc[4] += p1 * f.x; acc[5] += p1 * f.y;
            f = __half22float2(*(const __half2*)&rb.w); acc[6] += p1 * f.x; acc[7] += p1 * f.y;
        }
        if (j < mnb) {
            const int i0 = j + g;
            const int   s0 = __shfl(s, i0, 32);
            const float p0 = __shfl(p, i0, 32);
            const uint4 ra = *(const uint4*)(H + (long long)s0 * C + cl * 8);
            float2 f;
            f = __half22float2(*(const __half2*)&ra.x); acc[0] += p0 * f.x; acc[1] += p0 * f.y;
            f = __half22float2(*(const __half2*)&ra.y); acc[2] += p0 * f.x; acc[3] += p0 * f.y;
            f = __half22float2(*(const __half2*)&ra.z); acc[4] += p0 * f.x; acc[5] += p0 * f.y;
            f = __half22float2(*(const __half2*)&ra.w); acc[6] += p0 * f.x; acc[7] += p0 * f.y;
        }
    }
    // ssum within each half
#pragma unroll
    for (int off = 1; off < 32; off <<= 1)
        ssum += __shfl_xor(ssum, off, 64);
    const float inv = 1.f / (ssum + 1e-30f);

    // fold-reduce: 2 steps, lane ends owning channels ch, ch+1
    const int b0 = (ln >> 3) & 1, b1 = (ln >> 4) & 1;
    float s0 = b0 ? acc[0] : acc[4];
    float s1 = b0 ? acc[1] : acc[5];
    float s2 = b0 ? acc[2] : acc[6];
    float s3 = b0 ? acc[3] : acc[7];
    float r0 = __shfl_xor(s0, 8, 64);
    float r1 = __shfl_xor(s1, 8, 64);
    float r2 = __shfl_xor(s2, 8, 64);
    float r3 = __shfl_xor(s3, 8, 64);
    float a0 = (b0 ? acc[4] : acc[0]) + r0;
    float a1 = (b0 ? acc[5] : acc[1]) + r1;
    float a2 = (b0 ? acc[6] : acc[2]) + r2;
    float a3 = (b0 ? acc[7] : acc[3]) + r3;
    float t0 = b1 ? a0 : a2;
    float t1 = b1 ? a1 : a3;
    float q0 = __shfl_xor(t0, 16, 64);
    float q1 = __shfl_xor(t1, 16, 64);
    float c0v = (b1 ? a2 : a0) + q0;
    float c1v = (b1 ? a3 : a1) + q1;
    const int ch = cl * 8 + b0 * 4 + b1 * 2;

    // bias + ELU -> h2 row values
    float v0 = c0v * inv + bias[ch];
    float v1 = c1v * inv + bias[ch + 1];
    v0 = (v0 > 0.f) ? v0 : expm1f(v0);
    v1 = (v1 > 0.f) ? v1 : expm1f(v1);

    // ---- fused layer-2 GEMM ----
    const int w  = threadIdx.x >> 6;
    const int hf = lane >> 5;
    float2 hv2 = {v0, v1};
    *(float2*)&hrow[w][hf][ch] = hv2;    // intra-wave: ds_write then ds_read, in order

    float y = 0.f;
    const float* wp = W2 + ln;           // W2[ch][ln] = W2[ch*32+ln], coalesced per ch
#pragma unroll
    for (int cc = 0; cc < 64; cc += 4) {
        float4 hv = *(const float4*)&hrow[w][hf][cc];   // broadcast read
        y += hv.x * wp[(cc + 0) * 32] + hv.y * wp[(cc + 1) * 32]
           + hv.z * wp[(cc + 2) * 32] + hv.w * wp[(cc + 3) * 32];
    }
    // attention dots for layer 2
    float ts = y * a_src2[ln];
    float td = y * a_dst2[ln];
#pragma unroll
    for (int off = 1; off < 32; off <<= 1) {
        ts += __shfl_xor(ts, off, 64);
        td += __shfl_xor(td, off, 64);
    }
    if (nv) {
        g2[(long long)node * 32 + ln] = __float2half_rn(y);
        if (ln == 0) { as2[node] = ts; ad2[node] = td; }
    }
}

// ---------- layer-2 node pass: TWO NODES PER WAVE (round-8 form, C=32) ----------
template<int C, bool ELU>
__global__ __launch_bounds__(256) void k_node(
        const int* __restrict__ offs, const int* __restrict__ srt,
        const float* __restrict__ as_, const float* __restrict__ ad_,
        const __half* __restrict__ H, const float* __restrict__ bias,
        float* __restrict__ out) {
    constexpr int G  = C / 8;     // 4 for C=32
    constexpr int NR = 32 / G;    // 8
    const int wid = (int)(((long long)blockIdx.x * blockDim.x + threadIdx.x) >> 6);
    if (wid * 2 >= N_NODES) return;
    const int lane = threadIdx.x & 63;
    const int ln   = lane & 31;
    const int node = wid * 2 + (lane >> 5);
    const bool nv = node < N_NODES;
    const int beg = nv ? offs[node] : 0;
    const int end = nv ? offs[node + 1] : 0;
    const int deg = end - beg;
    const int mdeg = max(deg, __shfl_xor(deg, 32, 64));
    const float adn = nv ? ad_[node] : 0.f;
    const int g  = ln / G;
    const int cl = ln % G;
    float acc[8] = {};
    float ssum = 0.f;

    for (int base = 0; base < mdeg; base += 32) {
        const int nb  = min(32, deg - base);
        const int mnb = min(32, mdeg - base);
        int s = 0;
        float p = 0.f;
        if (ln < nb) {
            s = srt[beg + base + ln];
            float e = as_[s] + adn;
            e = (e > 0.f) ? e : NEG_SLOPE * e;
            p = __expf(e - MB_SHIFT);
        }
        ssum += p;
        int j = 0;
        for (; j + NR < mnb; j += 2 * NR) {
            const int i0 = j + g, i1 = j + NR + g;
            const int   s0 = __shfl(s, i0, 32);
            const int   s1 = __shfl(s, i1, 32);
            const float p0 = __shfl(p, i0, 32);
            const float p1 = __shfl(p, i1, 32);
            const uint4 ra = *(const uint4*)(H + (long long)s0 * C + cl * 8);
            const uint4 rb = *(const uint4*)(H + (long long)s1 * C + cl * 8);
            float2 f;
            f = __half22float2(*(const __half2*)&ra.x); acc[0] += p0 * f.x; acc[1] += p0 * f.y;
            f = __half22float2(*(const __half2*)&ra.y); acc[2] += p0 * f.x; acc[3] += p0 * f.y;
            f = __half22float2(*(const __half2*)&ra.z); acc[4] += p0 * f.x; acc[5] += p0 * f.y;
            f = __half22float2(*(const __half2*)&ra.w); acc[6] += p0 * f.x; acc[7] += p0 * f.y;
            f = __half22float2(*(const __half2*)&rb.x); acc[0] += p1 * f.x; acc[1] += p1 * f.y;
            f = __half22float2(*(const __half2*)&rb.y); acc[2] += p1 * f.x; acc[3] += p1 * f.y;
            f = __half22float2(*(const __half2*)&rb.z); acc[4] += p1 * f.x; acc[5] += p1 * f.y;
            f = __half22float2(*(const __half2*)&rb.w); acc[6] += p1 * f.x; acc[7] += p1 * f.y;
        }
        if (j < mnb) {
            const int i0 = j + g;
            const int   s0 = __shfl(s, i0, 32);
            const float p0 = __shfl(p, i0, 32);
            const uint4 ra = *(const uint4*)(H + (long long)s0 * C + cl * 8);
            float2 f;
            f = __half22float2(*(const __half2*)&ra.x); acc[0] += p0 * f.x; acc[1] += p0 * f.y;
            f = __half22float2(*(const __half2*)&ra.y); acc[2] += p0 * f.x; acc[3] += p0 * f.y;
            f = __half22float2(*(const __half2*)&ra.z); acc[4] += p0 * f.x; acc[5] += p0 * f.y;
            f = __half22float2(*(const __half2*)&ra.w); acc[6] += p0 * f.x; acc[7] += p0 * f.y;
        }
    }
#pragma unroll
    for (int off = 1; off < 32; off <<= 1)
        ssum += __shfl_xor(ssum, off, 64);
    const float inv = 1.f / (ssum + 1e-30f);

    // C=32: 8 row-groups per half -> 3 fold steps; lane owns 1 channel.
    const int b0 = (ln >> 2) & 1, b1 = (ln >> 3) & 1, b2 = (ln >> 4) & 1;
    float s0 = b0 ? acc[0] : acc[4];
    float s1 = b0 ? acc[1] : acc[5];
    float s2 = b0 ? acc[2] : acc[6];
    float s3 = b0 ? acc[3] : acc[7];
    float r0 = __shfl_xor(s0, 4, 64);
    float r1 = __shfl_xor(s1, 4, 64);
    float r2 = __shfl_xor(s2, 4, 64);
    float r3 = __shfl_xor(s3, 4, 64);
    float a0 = (b0 ? acc[4] : acc[0]) + r0;
    float a1 = (b0 ? acc[5] : acc[1]) + r1;
    float a2 = (b0 ? acc[6] : acc[2]) + r2;
    float a3 = (b0 ? acc[7] : acc[3]) + r3;
    float t0 = b1 ? a0 : a2;
    float t1 = b1 ? a1 : a3;
    float q0 = __shfl_xor(t0, 8, 64);
    float q1 = __shfl_xor(t1, 8, 64);
    float c0 = (b1 ? a2 : a0) + q0;
    float c1 = (b1 ? a3 : a1) + q1;
    float u = b2 ? c0 : c1;
    float ww = __shfl_xor(u, 16, 64);
    float v0 = (b2 ? c1 : c0) + ww;
    const int ch = cl * 8 + b0 * 4 + b1 * 2 + b2;
    if (nv) {
        float v = v0 * inv + bias[ch];
        if (ELU) v = (v > 0.f) ? v : expm1f(v);
        out[(long long)node * C + ch] = v;
    }
}

extern "C" void kernel_launch(void* const* d_in, const int* in_sizes, int n_in,
                              void* d_out, int out_size, void* d_ws, size_t ws_size,
                              hipStream_t stream) {
    const float* x      = (const float*)d_in[0];
    const void*  edges  = d_in[1];
    const float* W1     = (const float*)d_in[2];
    const float* a_src1 = (const float*)d_in[3];
    const float* a_dst1 = (const float*)d_in[4];
    const float* b1     = (const float*)d_in[5];
    const float* W2     = (const float*)d_in[6];
    const float* a_src2 = (const float*)d_in[7];
    const float* a_dst2 = (const float*)d_in[8];
    const float* b2     = (const float*)d_in[9];

    char* ws = (char*)d_ws;
    size_t off = 0;
    auto alloc = [&](size_t bytes) { char* p = ws + off; off += (bytes + 255) & ~size_t(255); return p; };
    __half*       h1      = (__half*)      alloc((size_t)N_NODES * 64 * 2);  // fp16 H, layer 1
    __half*       g2      = (__half*)      alloc((size_t)N_NODES * 32 * 2);  // fp16 h, layer 2 (no alias: k_node1 reads h1 while writing g2)
    float*        as1     = (float*)       alloc((size_t)N_NODES * 4);
    float*        ad1     = (float*)       alloc((size_t)N_NODES * 4);
    float*        as2     = (float*)       alloc((size_t)N_NODES * 4);
    float*        ad2     = (float*)       alloc((size_t)N_NODES * 4);
    int*          ghist   = (int*)         alloc((size_t)NBUCK * 4);
    int*          boffs   = (int*)         alloc((size_t)(NBUCK + 1) * 4);
    int*          gcur    = (int*)         alloc((size_t)NBUCK * 4);
    int*          offs    = (int*)         alloc((size_t)(N_NODES + 1) * 4);
    unsigned int* staging = (unsigned int*)alloc((size_t)TOT_E * 4);
    int*          srt     = (int*)         alloc((size_t)(TOT_E + 8) * 4);
    float*        out     = (float*)d_out;

    // two nodes per wave
    const int NODE_BLOCKS = (((N_NODES + 1) / 2) * 64 + 255) / 256;

    // binned CSR build front
    k_zero<<<(NBUCK + 255) / 256, 256, 0, stream>>>(ghist);
    k_binhist<<<416, 256, 0, stream>>>(edges, ghist);
    k_bscan<<<1, 256, 0, stream>>>(ghist, boffs, gcur);
    k_binscatter<<<NCHUNK, 256, 0, stream>>>(edges, gcur, staging);

    // merged: layer-1 GEMM + bucketsort
    k_sortgemm<<<NGEMM1 + NBUCK, 256, 0, stream>>>(
        staging, boffs, offs, srt, x, W1, a_src1, a_dst1, h1, as1, ad1);

    // layer-1 aggregation + ELU + FUSED layer-2 GEMM + att dots
    k_node1<<<NODE_BLOCKS, 256, 0, stream>>>(
        offs, srt, as1, ad1, h1, b1, W2, a_src2, a_dst2, g2, as2, ad2);

    // layer-2 aggregation -> final output
    k_node<32, false><<<NODE_BLOCKS, 256, 0, stream>>>(offs, srt, as2, ad2, g2, b2, out);
}

// Round 10
// 91.837 us; speedup vs baseline: 1.5682x; 1.2020x over previous
//
#include <hip/hip_runtime.h>
#include <hip/hip_fp16.h>

#define N_NODES 50000
#define N_EDGES 800000
#define TOT_E   (N_EDGES + N_NODES)
#define NEG_SLOPE 0.2f
#define MB_SHIFT 8.0f   // fixed softmax shift: valid upper bound for e=as+ad (|e|<~3);
                        // softmax is shift-invariant so result is exact up to fp rounding.

#define SHIFT  6
#define NBUCK  ((N_NODES + 63) >> SHIFT)       // 782 buckets of 64 nodes
#define NBP    1024                             // padded scan width
#define CAP    2048                             // fixed bucket capacity (E[load]=1088, ~29 sigma)
#define CHUNK  4096                             // 208 binscatter blocks
#define EPT    (CHUNK / 256)                    // 16 edges per thread
#define NCHUNK ((TOT_E + CHUNK - 1) / CHUNK)
#define NGEMM1 ((N_NODES + 127) / 128)          // 391 GEMM1 blocks (BM=128)

// ---------- edge fetch (handles int32 or int64 edge_index; self-loops appended) ----------
__device__ __forceinline__ void get_edge(const void* edges, int flag64, long long i,
                                         int& src, int& dst) {
    if (i < N_EDGES) {
        if (flag64) {
            const long long* e = (const long long*)edges;
            src = (int)e[i];
            dst = (int)e[N_EDGES + i];
        } else {
            const int* e = (const int*)edges;
            src = e[i];
            dst = e[(long long)N_EDGES + i];
        }
    } else {
        src = dst = (int)(i - N_EDGES);
    }
}

// per-block edge-dtype detection: wave 0 checks first 64 int64 slots, one ballot.
__device__ __forceinline__ int detect64(const void* edges, int tid, int* sfl) {
    if (tid < 64) {
        long long v = ((const long long*)edges)[tid];
        unsigned long long ok = __ballot(v >= 0 && v < N_NODES);
        if (tid == 0) *sfl = (ok == ~0ull) ? 1 : 0;
    }
    __syncthreads();
    return *sfl;
}

// ---------- zero the per-bucket cursor (3KB) ----------
__global__ __launch_bounds__(256) void k_zero(int* __restrict__ gcnt) {
    int i = blockIdx.x * blockDim.x + threadIdx.x;
    if (i < NBUCK) gcnt[i] = 0;
}

// ---------- chunked binscatter into FIXED-CAPACITY bucket regions ----------
// No histogram/scan pass: bucket b owns staging[b*CAP .. (b+1)*CAP); blocks reserve
// space with atomicAdd(gcnt[b]). k_node only needs (beg,deg) per node, so compactness
// is unnecessary -- removes k_binhist + k_bscan + a 6.8MB edge re-read.
__global__ __launch_bounds__(256) void k_binscatter(const void* edges,
                                                    int* gcnt, unsigned int* staging) {
    __shared__ int sc[NBP];        // counts -> inclusive scan
    __shared__ int so[NBP];        // original counts
    __shared__ int sr[NBUCK];      // running cursor (phase 3)
    __shared__ int gb[NBUCK];      // global base per bucket
    __shared__ unsigned int buf[CHUNK];
    __shared__ int sfl;
    const int tid = threadIdx.x;
    const int c0 = blockIdx.x * CHUNK;
    const int nE = min(CHUNK, TOT_E - c0);
    unsigned int pk[EPT];

    for (int s = 0; s < 4; s++) sc[tid + s * 256] = 0;
    for (int i = tid; i < NBUCK; i += 256) sr[i] = 0;
    const int fl = detect64(edges, tid, &sfl);   // includes __syncthreads()
    // phase 1: read edges, pack, count
#pragma unroll
    for (int j = 0; j < EPT; j++) {
        int li = j * 256 + tid;
        pk[j] = 0u;
        if (li < nE) {
            int src, dst;
            get_edge(edges, fl, (long long)(c0 + li), src, dst);
            pk[j] = ((unsigned int)dst << 16) | (unsigned int)src;
            atomicAdd(&sc[dst >> SHIFT], 1);
        }
    }
    __syncthreads();
    for (int s = 0; s < 4; s++) { int i = tid + s * 256; so[i] = sc[i]; }
    __syncthreads();
    // phase 2: inclusive scan of sc
    for (int off = 1; off < NBP; off <<= 1) {
        int t[4];
        for (int s = 0; s < 4; s++) {
            int a = tid + s * 256;
            t[s] = (a >= off) ? sc[a - off] : 0;
        }
        __syncthreads();
        for (int s = 0; s < 4; s++) sc[tid + s * 256] += t[s];
        __syncthreads();
    }
    // reserve ranges inside each bucket's fixed region
    for (int b = tid; b < NBUCK; b += 256)
        if (so[b]) gb[b] = b * CAP + atomicAdd(&gcnt[b], so[b]);
    __syncthreads();
    // phase 3: place packed edges bucket-grouped in LDS
#pragma unroll
    for (int j = 0; j < EPT; j++) {
        int li = j * 256 + tid;
        if (li < nE) {
            int b = pk[j] >> (16 + SHIFT);
            int lofs = sc[b] - so[b];
            int pos = lofs + atomicAdd(&sr[b], 1);
            buf[pos] = pk[j];
        }
    }
    __syncthreads();
    // phase 4: write out; consecutive p within a bucket -> consecutive global
    for (int p = tid; p < nE; p += 256) {
        unsigned int e = buf[p];
        int b = e >> (16 + SHIFT);
        int lofs = sc[b] - so[b];
        staging[gb[b] + (p - lofs)] = e;
    }
}

// ---------- merged dispatch: GEMM1 blocks (BM=128, 8x4 tile) + bucketsort blocks ----------
__global__ __launch_bounds__(256) void k_sortgemm(
        const unsigned int* __restrict__ staging, const int* __restrict__ gcnt,
        int* __restrict__ offs, int* __restrict__ degs, int* __restrict__ srt,
        const float* __restrict__ X, const float* __restrict__ W,
        const float* __restrict__ a_src, const float* __restrict__ a_dst,
        __half* __restrict__ H, float* __restrict__ as_, float* __restrict__ ad_) {
    const int tid = threadIdx.x;
    if (blockIdx.x >= NGEMM1) {
        // ----- bucketsort branch: staging bucket region -> node-grouped srt + offs/degs -----
        __shared__ int cnt[64];
        __shared__ int base[64];
        __shared__ int cur[64];
        const int b = blockIdx.x - NGEMM1;
        const int node0 = b << SHIFT;
        const int nn = min(64, N_NODES - node0);
        if (tid < 64) cnt[tid] = 0;
        __syncthreads();
        const int beg = b * CAP;
        const int end = beg + gcnt[b];
        for (int i = beg + tid; i < end; i += 256)
            atomicAdd(&cnt[(staging[i] >> 16) - node0], 1);
        __syncthreads();
        if (tid < 64) {
            int v = cnt[tid];
            int incl = v;
#pragma unroll
            for (int off = 1; off < 64; off <<= 1) {
                int t = __shfl_up(incl, off, 64);
                if (tid >= off) incl += t;
            }
            base[tid] = beg + incl - v;
            cur[tid] = 0;
            if (tid < nn) {
                offs[node0 + tid] = beg + incl - v;
                degs[node0 + tid] = v;
            }
        }
        __syncthreads();
        for (int i = beg + tid; i < end; i += 256) {
            unsigned int e = staging[i];
            int dl = (int)(e >> 16) - node0;
            int pos = base[dl] + atomicAdd(&cur[dl], 1);
            srt[pos] = (int)(e & 0xFFFFu);
        }
        return;
    }
    // ----- GEMM1 branch: K=128, N=64, BM=128, BK=32, 8x4 register tile -----
    // (8x4 tile: 3 ds_read_b128 per 32 FMAs vs 2 per 16 -- halves DS pressure/FMA.)
    constexpr int K = 128, N = 64, BM = 128, BK = 32;
    constexpr int TCOLS = N / 4;                 // 16
    constexpr int KPT = (BM * BK) / 256;         // 16
    __shared__ float Xs[BK][BM];
    __shared__ float Ws[BK][N];
    const int bid  = blockIdx.x;
    const int tcol = tid % TCOLS;
    const int trow = tid / TCOLS;                // 16 trows x 8 rows = 128
    const int node0 = bid * BM;
    const int r0 = trow * 8;
    const int c0 = tcol * 4;
    float acc[8][4] = {};

    const int sm = tid % BM;
    const int skb = (tid / BM) * KPT;            // 0 or 16
    const int srow = (node0 + sm < N_NODES) ? (node0 + sm) : (N_NODES - 1);

    for (int k0 = 0; k0 < K; k0 += BK) {
        const float* xp = X + (long long)srow * K + k0 + skb;
#pragma unroll
        for (int j = 0; j < KPT; j += 4) {
            float4 v = *(const float4*)(xp + j);
            Xs[skb + j + 0][sm] = v.x;
            Xs[skb + j + 1][sm] = v.y;
            Xs[skb + j + 2][sm] = v.z;
            Xs[skb + j + 3][sm] = v.w;
        }
#pragma unroll
        for (int i = tid; i < BK * N / 4; i += 256)
            ((float4*)Ws)[i] = ((const float4*)W)[(k0 * N) / 4 + i];
        __syncthreads();
#pragma unroll 4
        for (int k = 0; k < BK; ++k) {
            float4 xa = *(const float4*)&Xs[k][r0];
            float4 xb = *(const float4*)&Xs[k][r0 + 4];
            float4 wb = *(const float4*)&Ws[k][c0];
            float xr[8] = {xa.x, xa.y, xa.z, xa.w, xb.x, xb.y, xb.z, xb.w};
            float wc[4] = {wb.x, wb.y, wb.z, wb.w};
#pragma unroll
            for (int i = 0; i < 8; ++i)
#pragma unroll
                for (int j = 0; j < 4; ++j)
                    acc[i][j] += xr[i] * wc[j];
        }
        __syncthreads();
    }

    const float4 asv = *(const float4*)(a_src + c0);
    const float4 adv = *(const float4*)(a_dst + c0);
    const int rbase = node0 + r0;
    float vsr[8], vdr[8];
#pragma unroll
    for (int i = 0; i < 8; ++i) {
        float vs = acc[i][0] * asv.x + acc[i][1] * asv.y + acc[i][2] * asv.z + acc[i][3] * asv.w;
        float vd = acc[i][0] * adv.x + acc[i][1] * adv.y + acc[i][2] * adv.z + acc[i][3] * adv.w;
#pragma unroll
        for (int off = 1; off < TCOLS; off <<= 1) {
            vs += __shfl_xor(vs, off, 64);
            vd += __shfl_xor(vd, off, 64);
        }
        vsr[i] = vs; vdr[i] = vd;
        if (rbase + i < N_NODES) {
            __half2 q0 = __floats2half2_rn(acc[i][0], acc[i][1]);
            __half2 q1 = __floats2half2_rn(acc[i][2], acc[i][3]);
            uint2 raw;
            raw.x = *(unsigned int*)&q0;
            raw.y = *(unsigned int*)&q1;
            *(uint2*)(H + (long long)(rbase + i) * N + c0) = raw;
        }
    }
    if (tcol == 0) {
#pragma unroll
        for (int i = 0; i < 8; ++i) {
            if (rbase + i < N_NODES) {
                as_[rbase + i] = vsr[i];
                ad_[rbase + i] = vdr[i];
            }
        }
    }
}

// ---------- layer-1 node pass, TWO NODES PER WAVE, with FUSED layer-2 GEMM ----------
__global__ __launch_bounds__(256) void k_node1(
        const int* __restrict__ offs, const int* __restrict__ degs,
        const int* __restrict__ srt,
        const float* __restrict__ as_, const float* __restrict__ ad_,
        const __half* __restrict__ H, const float* __restrict__ bias,
        const float* __restrict__ W2, const float* __restrict__ a_src2,
        const float* __restrict__ a_dst2,
        __half* __restrict__ g2, float* __restrict__ as2, float* __restrict__ ad2) {
    constexpr int C = 64, G = 8, NR = 4;   // G lanes/row, NR rows per slot per node
    __shared__ float hrow[4][2][64];       // [wave-in-block][half][channel]
    const int wid = (int)(((long long)blockIdx.x * blockDim.x + threadIdx.x) >> 6);
    if (wid * 2 >= N_NODES) return;
    const int lane = threadIdx.x & 63;
    const int ln   = lane & 31;
    const int node = wid * 2 + (lane >> 5);
    const bool nv = node < N_NODES;
    const int beg = nv ? offs[node] : 0;
    const int deg = nv ? degs[node] : 0;
    const int mdeg = max(deg, __shfl_xor(deg, 32, 64));
    const float adn = nv ? ad_[node] : 0.f;
    const int g  = ln / G;
    const int cl = ln % G;
    float acc[8] = {};
    float ssum = 0.f;

    for (int base = 0; base < mdeg; base += 32) {
        const int nb  = min(32, deg - base);
        const int mnb = min(32, mdeg - base);
        // ---- phase A ----
        int s = 0;
        float p = 0.f;
        if (ln < nb) {
            s = srt[beg + base + ln];
            float e = as_[s] + adn;
            e = (e > 0.f) ? e : NEG_SLOPE * e;
            p = __expf(e - MB_SHIFT);
        }
        ssum += p;
        // ---- phase B ----
        int j = 0;
        for (; j + NR < mnb; j += 2 * NR) {
            const int i0 = j + g, i1 = j + NR + g;
            const int   s0 = __shfl(s, i0, 32);
            const int   s1 = __shfl(s, i1, 32);
            const float p0 = __shfl(p, i0, 32);
            const float p1 = __shfl(p, i1, 32);
            const uint4 ra = *(const uint4*)(H + (long long)s0 * C + cl * 8);
            const uint4 rb = *(const uint4*)(H + (long long)s1 * C + cl * 8);
            float2 f;
            f = __half22float2(*(const __half2*)&ra.x); acc[0] += p0 * f.x; acc[1] += p0 * f.y;
            f = __half22float2(*(const __half2*)&ra.y); acc[2] += p0 * f.x; acc[3] += p0 * f.y;
            f = __half22float2(*(const __half2*)&ra.z); acc[4] += p0 * f.x; acc[5] += p0 * f.y;
            f = __half22float2(*(const __half2*)&ra.w); acc[6] += p0 * f.x; acc[7] += p0 * f.y;
            f = __half22float2(*(const __half2*)&rb.x); acc[0] += p1 * f.x; acc[1] += p1 * f.y;
            f = __half22float2(*(const __half2*)&rb.y); acc[2] += p1 * f.x; acc[3] += p1 * f.y;
            f = __half22float2(*(const __half2*)&rb.z); acc[4] += p1 * f.x; acc[5] += p1 * f.y;
            f = __half22float2(*(const __half2*)&rb.w); acc[6] += p1 * f.x; acc[7] += p1 * f.y;
        }
        if (j < mnb) {
            const int i0 = j + g;
            const int   s0 = __shfl(s, i0, 32);
            const float p0 = __shfl(p, i0, 32);
            const uint4 ra = *(const uint4*)(H + (long long)s0 * C + cl * 8);
            float2 f;
            f = __half22float2(*(const __half2*)&ra.x); acc[0] += p0 * f.x; acc[1] += p0 * f.y;
            f = __half22float2(*(const __half2*)&ra.y); acc[2] += p0 * f.x; acc[3] += p0 * f.y;
            f = __half22float2(*(const __half2*)&ra.z); acc[4] += p0 * f.x; acc[5] += p0 * f.y;
            f = __half22float2(*(const __half2*)&ra.w); acc[6] += p0 * f.x; acc[7] += p0 * f.y;
        }
    }
    // ssum within each half
#pragma unroll
    for (int off = 1; off < 32; off <<= 1)
        ssum += __shfl_xor(ssum, off, 64);
    const float inv = 1.f / (ssum + 1e-30f);

    // fold-reduce: 2 steps, lane ends owning channels ch, ch+1
    const int b0 = (ln >> 3) & 1, b1 = (ln >> 4) & 1;
    float s0 = b0 ? acc[0] : acc[4];
    float s1 = b0 ? acc[1] : acc[5];
    float s2 = b0 ? acc[2] : acc[6];
    float s3 = b0 ? acc[3] : acc[7];
    float r0 = __shfl_xor(s0, 8, 64);
    float r1 = __shfl_xor(s1, 8, 64);
    float r2 = __shfl_xor(s2, 8, 64);
    float r3 = __shfl_xor(s3, 8, 64);
    float a0 = (b0 ? acc[4] : acc[0]) + r0;
    float a1 = (b0 ? acc[5] : acc[1]) + r1;
    float a2 = (b0 ? acc[6] : acc[2]) + r2;
    float a3 = (b0 ? acc[7] : acc[3]) + r3;
    float t0 = b1 ? a0 : a2;
    float t1 = b1 ? a1 : a3;
    float q0 = __shfl_xor(t0, 16, 64);
    float q1 = __shfl_xor(t1, 16, 64);
    float c0v = (b1 ? a2 : a0) + q0;
    float c1v = (b1 ? a3 : a1) + q1;
    const int ch = cl * 8 + b0 * 4 + b1 * 2;

    // bias + ELU -> h2 row values
    float v0 = c0v * inv + bias[ch];
    float v1 = c1v * inv + bias[ch + 1];
    v0 = (v0 > 0.f) ? v0 : expm1f(v0);
    v1 = (v1 > 0.f) ? v1 : expm1f(v1);

    // ---- fused layer-2 GEMM ----
    const int w  = threadIdx.x >> 6;
    const int hf = lane >> 5;
    float2 hv2 = {v0, v1};
    *(float2*)&hrow[w][hf][ch] = hv2;    // intra-wave: ds_write then ds_read, in order

    float y = 0.f;
    const float* wp = W2 + ln;           // W2[ch][ln] = W2[ch*32+ln], coalesced per ch
#pragma unroll
    for (int cc = 0; cc < 64; cc += 4) {
        float4 hv = *(const float4*)&hrow[w][hf][cc];   // broadcast read
        y += hv.x * wp[(cc + 0) * 32] + hv.y * wp[(cc + 1) * 32]
           + hv.z * wp[(cc + 2) * 32] + hv.w * wp[(cc + 3) * 32];
    }
    // attention dots for layer 2
    float ts = y * a_src2[ln];
    float td = y * a_dst2[ln];
#pragma unroll
    for (int off = 1; off < 32; off <<= 1) {
        ts += __shfl_xor(ts, off, 64);
        td += __shfl_xor(td, off, 64);
    }
    if (nv) {
        g2[(long long)node * 32 + ln] = __float2half_rn(y);
        if (ln == 0) { as2[node] = ts; ad2[node] = td; }
    }
}

// ---------- layer-2 node pass: TWO NODES PER WAVE (C=32) ----------
template<int C, bool ELU>
__global__ __launch_bounds__(256) void k_node(
        const int* __restrict__ offs, const int* __restrict__ degs,
        const int* __restrict__ srt,
        const float* __restrict__ as_, const float* __restrict__ ad_,
        const __half* __restrict__ H, const float* __restrict__ bias,
        float* __restrict__ out) {
    constexpr int G  = C / 8;     // 4 for C=32
    constexpr int NR = 32 / G;    // 8
    const int wid = (int)(((long long)blockIdx.x * blockDim.x + threadIdx.x) >> 6);
    if (wid * 2 >= N_NODES) return;
    const int lane = threadIdx.x & 63;
    const int ln   = lane & 31;
    const int node = wid * 2 + (lane >> 5);
    const bool nv = node < N_NODES;
    const int beg = nv ? offs[node] : 0;
    const int deg = nv ? degs[node] : 0;
    const int mdeg = max(deg, __shfl_xor(deg, 32, 64));
    const float adn = nv ? ad_[node] : 0.f;
    const int g  = ln / G;
    const int cl = ln % G;
    float acc[8] = {};
    float ssum = 0.f;

    for (int base = 0; base < mdeg; base += 32) {
        const int nb  = min(32, deg - base);
        const int mnb = min(32, mdeg - base);
        int s = 0;
        float p = 0.f;
        if (ln < nb) {
            s = srt[beg + base + ln];
            float e = as_[s] + adn;
            e = (e > 0.f) ? e : NEG_SLOPE * e;
            p = __expf(e - MB_SHIFT);
        }
        ssum += p;
        int j = 0;
        for (; j + NR < mnb; j += 2 * NR) {
            const int i0 = j + g, i1 = j + NR + g;
            const int   s0 = __shfl(s, i0, 32);
            const int   s1 = __shfl(s, i1, 32);
            const float p0 = __shfl(p, i0, 32);
            const float p1 = __shfl(p, i1, 32);
            const uint4 ra = *(const uint4*)(H + (long long)s0 * C + cl * 8);
            const uint4 rb = *(const uint4*)(H + (long long)s1 * C + cl * 8);
            float2 f;
            f = __half22float2(*(const __half2*)&ra.x); acc[0] += p0 * f.x; acc[1] += p0 * f.y;
            f = __half22float2(*(const __half2*)&ra.y); acc[2] += p0 * f.x; acc[3] += p0 * f.y;
            f = __half22float2(*(const __half2*)&ra.z); acc[4] += p0 * f.x; acc[5] += p0 * f.y;
            f = __half22float2(*(const __half2*)&ra.w); acc[6] += p0 * f.x; acc[7] += p0 * f.y;
            f = __half22float2(*(const __half2*)&rb.x); acc[0] += p1 * f.x; acc[1] += p1 * f.y;
            f = __half22float2(*(const __half2*)&rb.y); acc[2] += p1 * f.x; acc[3] += p1 * f.y;
            f = __half22float2(*(const __half2*)&rb.z); acc[4] += p1 * f.x; acc[5] += p1 * f.y;
            f = __half22float2(*(const __half2*)&rb.w); acc[6] += p1 * f.x; acc[7] += p1 * f.y;
        }
        if (j < mnb) {
            const int i0 = j + g;
            const int   s0 = __shfl(s, i0, 32);
            const float p0 = __shfl(p, i0, 32);
            const uint4 ra = *(const uint4*)(H + (long long)s0 * C + cl * 8);
            float2 f;
            f = __half22float2(*(const __half2*)&ra.x); acc[0] += p0 * f.x; acc[1] += p0 * f.y;
            f = __half22float2(*(const __half2*)&ra.y); acc[2] += p0 * f.x; acc[3] += p0 * f.y;
            f = __half22float2(*(const __half2*)&ra.z); acc[4] += p0 * f.x; acc[5] += p0 * f.y;
            f = __half22float2(*(const __half2*)&ra.w); acc[6] += p0 * f.x; acc[7] += p0 * f.y;
        }
    }
#pragma unroll
    for (int off = 1; off < 32; off <<= 1)
        ssum += __shfl_xor(ssum, off, 64);
    const float inv = 1.f / (ssum + 1e-30f);

    // C=32: 8 row-groups per half -> 3 fold steps; lane owns 1 channel.
    const int b0 = (ln >> 2) & 1, b1 = (ln >> 3) & 1, b2 = (ln >> 4) & 1;
    float s0 = b0 ? acc[0] : acc[4];
    float s1 = b0 ? acc[1] : acc[5];
    float s2 = b0 ? acc[2] : acc[6];
    float s3 = b0 ? acc[3] : acc[7];
    float r0 = __shfl_xor(s0, 4, 64);
    float r1 = __shfl_xor(s1, 4, 64);
    float r2 = __shfl_xor(s2, 4, 64);
    float r3 = __shfl_xor(s3, 4, 64);
    float a0 = (b0 ? acc[4] : acc[0]) + r0;
    float a1 = (b0 ? acc[5] : acc[1]) + r1;
    float a2 = (b0 ? acc[6] : acc[2]) + r2;
    float a3 = (b0 ? acc[7] : acc[3]) + r3;
    float t0 = b1 ? a0 : a2;
    float t1 = b1 ? a1 : a3;
    float q0 = __shfl_xor(t0, 8, 64);
    float q1 = __shfl_xor(t1, 8, 64);
    float c0 = (b1 ? a2 : a0) + q0;
    float c1 = (b1 ? a3 : a1) + q1;
    float u = b2 ? c0 : c1;
    float ww = __shfl_xor(u, 16, 64);
    float v0 = (b2 ? c1 : c0) + ww;
    const int ch = cl * 8 + b0 * 4 + b1 * 2 + b2;
    if (nv) {
        float v = v0 * inv + bias[ch];
        if (ELU) v = (v > 0.f) ? v : expm1f(v);
        out[(long long)node * C + ch] = v;
    }
}

extern "C" void kernel_launch(void* const* d_in, const int* in_sizes, int n_in,
                              void* d_out, int out_size, void* d_ws, size_t ws_size,
                              hipStream_t stream) {
    const float* x      = (const float*)d_in[0];
    const void*  edges  = d_in[1];
    const float* W1     = (const float*)d_in[2];
    const float* a_src1 = (const float*)d_in[3];
    const float* a_dst1 = (const float*)d_in[4];
    const float* b1     = (const float*)d_in[5];
    const float* W2     = (const float*)d_in[6];
    const float* a_src2 = (const float*)d_in[7];
    const float* a_dst2 = (const float*)d_in[8];
    const float* b2     = (const float*)d_in[9];

    char* ws = (char*)d_ws;
    size_t off = 0;
    auto alloc = [&](size_t bytes) { char* p = ws + off; off += (bytes + 255) & ~size_t(255); return p; };
    __half*       h1      = (__half*)      alloc((size_t)N_NODES * 64 * 2);  // fp16 H, layer 1
    __half*       g2      = (__half*)      alloc((size_t)N_NODES * 32 * 2);  // fp16 h, layer 2
    float*        as1     = (float*)       alloc((size_t)N_NODES * 4);
    float*        ad1     = (float*)       alloc((size_t)N_NODES * 4);
    float*        as2     = (float*)       alloc((size_t)N_NODES * 4);
    float*        ad2     = (float*)       alloc((size_t)N_NODES * 4);
    int*          gcnt    = (int*)         alloc((size_t)NBUCK * 4);
    int*          offs    = (int*)         alloc((size_t)N_NODES * 4);
    int*          degs    = (int*)         alloc((size_t)N_NODES * 4);
    unsigned int* staging = (unsigned int*)alloc((size_t)NBUCK * CAP * 4);   // 6.4MB
    int*          srt     = (int*)         alloc((size_t)NBUCK * CAP * 4);   // 6.4MB
    float*        out     = (float*)d_out;

    // two nodes per wave
    const int NODE_BLOCKS = (((N_NODES + 1) / 2) * 64 + 255) / 256;

    // CSR build front: zero cursors, then single-pass fixed-capacity binscatter
    k_zero<<<(NBUCK + 255) / 256, 256, 0, stream>>>(gcnt);
    k_binscatter<<<NCHUNK, 256, 0, stream>>>(edges, gcnt, staging);

    // merged: layer-1 GEMM (BM=128, 8x4 tile) + bucketsort
    k_sortgemm<<<NGEMM1 + NBUCK, 256, 0, stream>>>(
        staging, gcnt, offs, degs, srt, x, W1, a_src1, a_dst1, h1, as1, ad1);

    // layer-1 aggregation + ELU + FUSED layer-2 GEMM + att dots
    k_node1<<<NODE_BLOCKS, 256, 0, stream>>>(
        offs, degs, srt, as1, ad1, h1, b1, W2, a_src2, a_dst2, g2, as2, ad2);

    // layer-2 aggregation -> final output
    k_node<32, false><<<NODE_BLOCKS, 256, 0, stream>>>(offs, degs, srt, as2, ad2, g2, b2, out);
}